// Round 1
// baseline (139.439 us; speedup 1.0000x reference)
//
#include <hip/hip_runtime.h>
#include <hip/hip_bf16.h>

typedef __bf16 bf16_t;
typedef __bf16 bf16x8 __attribute__((ext_vector_type(8)));
typedef float f32x4 __attribute__((ext_vector_type(4)));

#define B_   8
#define C_   512
#define HW_  1024
#define NPIX 8192

// ---- async global->LDS (16B per lane) ----
typedef __attribute__((address_space(3))) void lds_vp;
typedef const __attribute__((address_space(1))) void gbl_vp;
__device__ __forceinline__ void gload_lds16(const void* g, void* l) {
    __builtin_amdgcn_global_load_lds((gbl_vp*)g, (lds_vp*)l, 16, 0, 0);
}

// Stage a 128x64 bf16 tile (row-major, ld=ldk) into LDS [128][64] linearly.
// 256 threads: 4 passes x 256 lanes x 16B. LDS dest must be wave-uniform base.
__device__ __forceinline__ void stage128x64(const bf16_t* __restrict__ g, int ldk,
                                            bf16_t* lds, int tid) {
    int w64 = tid & ~63;          // wave-uniform thread base
#pragma unroll
    for (int s = 0; s < 4; ++s) {
        int u = s * 256 + tid;    // per-lane unit: row = u>>3, 16B-chunk = u&7
        const bf16_t* src = g + (size_t)(u >> 3) * ldk + (u & 7) * 8;
        gload_lds16((const void*)src, (void*)(lds + (size_t)(s * 256 + w64) * 8));
    }
}

// ---- K1a: convert weights to bf16 ----
__global__ void k_cvt_w(const float* __restrict__ Wq, const float* __restrict__ Wk,
                        bf16_t* __restrict__ wq, bf16_t* __restrict__ wk) {
    int i = blockIdx.x * 256 + threadIdx.x;   // grid covers 512*512
    wq[i] = (bf16_t)Wq[i];
    wk[i] = (bf16_t)Wk[i];
}

// ---- K1b: x [B,C,HW] f32 -> xT [B*HW, C] bf16 (per-image transpose) ----
__global__ void k_transpose(const float* __restrict__ x, bf16_t* __restrict__ xT) {
    __shared__ bf16_t tile[64 * 66];
    int p0 = blockIdx.x * 64, c0 = blockIdx.y * 64, b = blockIdx.z;
    int t = threadIdx.x;
#pragma unroll
    for (int s = 0; s < 16; ++s) {
        int u = s * 256 + t;
        int cr = u >> 6, pc = u & 63;
        tile[cr * 66 + pc] = (bf16_t)x[((size_t)(b * C_ + c0 + cr)) * HW_ + p0 + pc];
    }
    __syncthreads();
#pragma unroll
    for (int s = 0; s < 16; ++s) {
        int u = s * 256 + t;
        int pr = u >> 6, cc = u & 63;
        xT[((size_t)(b * HW_ + p0 + pr)) * C_ + c0 + cc] = tile[cc * 66 + pr];
    }
}

// ---- K2: q/k projection GEMM: [8192,512] = xT @ W^T + b, output bf16 ----
__launch_bounds__(256, 2)
__global__ void k_gemm_qk(const bf16_t* __restrict__ xT,
                          const bf16_t* __restrict__ wq, const bf16_t* __restrict__ wk,
                          const float* __restrict__ bq, const float* __restrict__ bk,
                          bf16_t* __restrict__ qo, bf16_t* __restrict__ ko) {
    __shared__ bf16_t As[128 * 64];
    __shared__ bf16_t Bs[128 * 64];
    int bid = blockIdx.x;
    int mtile = bid >> 3;             // 0..63
    int nt = bid & 7;                 // 0..3 -> q cols, 4..7 -> k cols
    const bf16_t* wsel = (nt < 4) ? wq : wk;
    const float*  bsel = (nt < 4) ? bq : bk;
    bf16_t*       osel = (nt < 4) ? qo : ko;
    int nb = (nt & 3) * 128;
    int i0 = mtile * 128;
    int tid = threadIdx.x;
    int lane = tid & 63, w = tid >> 6;
    int wr = w >> 1, wc = w & 1, lr = lane & 15, lg = lane >> 4;

    f32x4 acc[4][4];
#pragma unroll
    for (int mi = 0; mi < 4; ++mi)
#pragma unroll
        for (int ni = 0; ni < 4; ++ni)
#pragma unroll
            for (int r = 0; r < 4; ++r) acc[mi][ni][r] = 0.f;

    for (int kt = 0; kt < 8; ++kt) {
        int k0 = kt * 64;
        stage128x64(xT + (size_t)i0 * 512 + k0, 512, As, tid);
        stage128x64(wsel + (size_t)nb * 512 + k0, 512, Bs, tid);
        __syncthreads();
#pragma unroll
        for (int kk = 0; kk < 2; ++kk) {
            bf16x8 af[4], bfr[4];
#pragma unroll
            for (int mi = 0; mi < 4; ++mi)
                af[mi] = *reinterpret_cast<const bf16x8*>(
                    &As[(wr * 64 + mi * 16 + lr) * 64 + kk * 32 + lg * 8]);
#pragma unroll
            for (int ni = 0; ni < 4; ++ni)
                bfr[ni] = *reinterpret_cast<const bf16x8*>(
                    &Bs[(wc * 64 + ni * 16 + lr) * 64 + kk * 32 + lg * 8]);
#pragma unroll
            for (int mi = 0; mi < 4; ++mi)
#pragma unroll
                for (int ni = 0; ni < 4; ++ni)
                    acc[mi][ni] = __builtin_amdgcn_mfma_f32_16x16x32_bf16(
                        af[mi], bfr[ni], acc[mi][ni], 0, 0, 0);
        }
        __syncthreads();
    }
#pragma unroll
    for (int ni = 0; ni < 4; ++ni) {
        int col = nb + wc * 64 + ni * 16 + lr;
        float bias = bsel[col];
#pragma unroll
        for (int mi = 0; mi < 4; ++mi) {
            int rowb = i0 + wr * 64 + mi * 16 + lg * 4;
#pragma unroll
            for (int r = 0; r < 4; ++r)
                osel[(size_t)(rowb + r) * 512 + col] = (bf16_t)(acc[mi][ni][r] + bias);
        }
    }
}

// ---- K3: score GEMM + per-key-image max, never materializing S ----
// block = (128 query rows) x (one key image of 1024 cols), K=512
__launch_bounds__(256, 2)
__global__ void k_gemm_max(const bf16_t* __restrict__ q, const bf16_t* __restrict__ k,
                           float* __restrict__ Mout) {
    __shared__ bf16_t As[128 * 64];
    __shared__ bf16_t Bs[128 * 64];
    __shared__ float sm[2][128];
    int bid = blockIdx.x;
    int mtile = bid >> 3, bimg = bid & 7;
    int i0 = mtile * 128;
    int j0 = bimg * 1024;
    int tid = threadIdx.x, lane = tid & 63, w = tid >> 6;
    int wr = w >> 1, wc = w & 1, lr = lane & 15, lg = lane >> 4;

    float rmax[4][4];
#pragma unroll
    for (int mi = 0; mi < 4; ++mi)
#pragma unroll
        for (int r = 0; r < 4; ++r) rmax[mi][r] = -3.4e38f;

    for (int ns = 0; ns < 8; ++ns) {
        f32x4 acc[4][4];
#pragma unroll
        for (int mi = 0; mi < 4; ++mi)
#pragma unroll
            for (int ni = 0; ni < 4; ++ni)
#pragma unroll
                for (int r = 0; r < 4; ++r) acc[mi][ni][r] = 0.f;

        for (int kt = 0; kt < 8; ++kt) {
            stage128x64(q + (size_t)i0 * 512 + kt * 64, 512, As, tid);
            stage128x64(k + (size_t)(j0 + ns * 128) * 512 + kt * 64, 512, Bs, tid);
            __syncthreads();
#pragma unroll
            for (int kk = 0; kk < 2; ++kk) {
                bf16x8 af[4], bfr[4];
#pragma unroll
                for (int mi = 0; mi < 4; ++mi)
                    af[mi] = *reinterpret_cast<const bf16x8*>(
                        &As[(wr * 64 + mi * 16 + lr) * 64 + kk * 32 + lg * 8]);
#pragma unroll
                for (int ni = 0; ni < 4; ++ni)
                    bfr[ni] = *reinterpret_cast<const bf16x8*>(
                        &Bs[(wc * 64 + ni * 16 + lr) * 64 + kk * 32 + lg * 8]);
#pragma unroll
                for (int mi = 0; mi < 4; ++mi)
#pragma unroll
                    for (int ni = 0; ni < 4; ++ni)
                        acc[mi][ni] = __builtin_amdgcn_mfma_f32_16x16x32_bf16(
                            af[mi], bfr[ni], acc[mi][ni], 0, 0, 0);
            }
            __syncthreads();
        }
#pragma unroll
        for (int mi = 0; mi < 4; ++mi)
#pragma unroll
            for (int ni = 0; ni < 4; ++ni)
#pragma unroll
                for (int r = 0; r < 4; ++r)
                    rmax[mi][r] = fmaxf(rmax[mi][r], acc[mi][ni][r]);
    }
    // reduce across the 16 lanes that share a row (lane&15 enumerate columns)
#pragma unroll
    for (int mi = 0; mi < 4; ++mi)
#pragma unroll
        for (int r = 0; r < 4; ++r) {
            float v = rmax[mi][r];
#pragma unroll
            for (int off = 1; off < 16; off <<= 1) v = fmaxf(v, __shfl_xor(v, off));
            rmax[mi][r] = v;
        }
    if (lr == 0) {
#pragma unroll
        for (int mi = 0; mi < 4; ++mi)
#pragma unroll
            for (int r = 0; r < 4; ++r)
                sm[wc][wr * 64 + mi * 16 + lg * 4 + r] = rmax[mi][r];
    }
    __syncthreads();
    if (tid < 128) {
        float v = fmaxf(sm[0][tid], sm[1][tid]);
        Mout[(size_t)(i0 + tid) * 8 + bimg] = v;
    }
}

// ---- K4: mean over key images, scale, softmax per query image ----
__global__ void k_softmax(const float* __restrict__ Mout, float* __restrict__ wsm) {
    int b = blockIdx.x;       // 8 blocks
    int t = threadIdx.x;      // 256
    __shared__ float red[16];
    const float scale = 0.044194173824159216f;  // 1/sqrt(512)
    float s[4];
#pragma unroll
    for (int i = 0; i < 4; ++i) {
        int p = t + i * 256;
        const float* row = &Mout[(size_t)(b * 1024 + p) * 8];
        float acc = 0.f;
#pragma unroll
        for (int j = 0; j < 8; ++j) acc += row[j];
        s[i] = acc * (scale / 8.0f);
    }
    float m = fmaxf(fmaxf(s[0], s[1]), fmaxf(s[2], s[3]));
#pragma unroll
    for (int off = 1; off < 64; off <<= 1) m = fmaxf(m, __shfl_xor(m, off));
    if ((t & 63) == 0) red[t >> 6] = m;
    __syncthreads();
    float m4 = fmaxf(fmaxf(red[0], red[1]), fmaxf(red[2], red[3]));
    float e[4], sum = 0.f;
#pragma unroll
    for (int i = 0; i < 4; ++i) { e[i] = __expf(s[i] - m4); sum += e[i]; }
#pragma unroll
    for (int off = 1; off < 64; off <<= 1) sum += __shfl_xor(sum, off);
    if ((t & 63) == 0) red[8 + (t >> 6)] = sum;
    __syncthreads();
    float tot = red[8] + red[9] + red[10] + red[11];
    float inv = 1.0f / tot;
#pragma unroll
    for (int i = 0; i < 4; ++i) wsm[b * 1024 + t + i * 256] = e[i] * inv;
}

// ---- K5: y[c] = mean_{b,p} x[b,c,p] * w[b,p] ----
__global__ void k_reduce_y(const float* __restrict__ x, const float* __restrict__ wsm,
                           float* __restrict__ y) {
    int c = blockIdx.x;   // 512
    int t = threadIdx.x;  // 256
    float acc = 0.f;
    for (int b = 0; b < 8; ++b) {
        const float* xb = x + ((size_t)(b * C_ + c)) * HW_;
        const float* wb = wsm + b * HW_;
#pragma unroll
        for (int i = 0; i < 4; ++i) {
            int p = t + i * 256;
            acc += xb[p] * wb[p];
        }
    }
#pragma unroll
    for (int off = 1; off < 64; off <<= 1) acc += __shfl_xor(acc, off);
    __shared__ float red[4];
    if ((t & 63) == 0) red[t >> 6] = acc;
    __syncthreads();
    if (t == 0) y[c] = (red[0] + red[1] + red[2] + red[3]) * (1.0f / 8192.0f);
}

// ---- K6: x_proto[d] = W6[d,:] . y + b6[d] ----
__global__ void k_proto(const float* __restrict__ W6, const float* __restrict__ b6,
                        const float* __restrict__ y, float* __restrict__ proto) {
    int d = blockIdx.x;       // 512
    int lane = threadIdx.x;   // 64
    float acc = 0.f;
#pragma unroll
    for (int i = 0; i < 8; ++i)
        acc += W6[(size_t)d * C_ + lane + i * 64] * y[lane + i * 64];
#pragma unroll
    for (int off = 1; off < 64; off <<= 1) acc += __shfl_xor(acc, off);
    if (lane == 0) proto[d] = acc + b6[d];
}

// ---- K7: out = x * proto[c] ----
__global__ void k_final(const float* __restrict__ x, const float* __restrict__ proto,
                        float* __restrict__ out) {
    int idx = blockIdx.x * 256 + threadIdx.x;  // over 1048576 float4 units
    float4 v = ((const float4*)x)[idx];
    int c = (idx >> 8) & 511;
    float p = proto[c];
    v.x *= p; v.y *= p; v.z *= p; v.w *= p;
    ((float4*)out)[idx] = v;
}

extern "C" void kernel_launch(void* const* d_in, const int* in_sizes, int n_in,
                              void* d_out, int out_size, void* d_ws, size_t ws_size,
                              hipStream_t stream) {
    const float* x  = (const float*)d_in[0];
    const float* Wq = (const float*)d_in[1];
    const float* bq = (const float*)d_in[2];
    const float* Wk = (const float*)d_in[3];
    const float* bk = (const float*)d_in[4];
    const float* W6 = (const float*)d_in[5];
    const float* b6 = (const float*)d_in[6];
    float* out = (float*)d_out;

    char* ws = (char*)d_ws;
    bf16_t* xT    = (bf16_t*)(ws);                 // 8192*512*2   = 8388608
    bf16_t* wqb   = (bf16_t*)(ws + 8388608);       // 512*512*2    = 524288
    bf16_t* wkb   = (bf16_t*)(ws + 8912896);       // 524288
    bf16_t* qb    = (bf16_t*)(ws + 9437184);       // 8388608
    bf16_t* kb    = (bf16_t*)(ws + 17825792);      // 8388608
    float*  Mout  = (float*)(ws + 26214400);       // 8192*8*4     = 262144
    float*  wsm   = (float*)(ws + 26476544);       // 8*1024*4     = 32768
    float*  yv    = (float*)(ws + 26509312);       // 2048
    float*  proto = (float*)(ws + 26511360);       // 2048

    hipLaunchKernelGGL(k_cvt_w, dim3(1024), dim3(256), 0, stream, Wq, Wk, wqb, wkb);
    hipLaunchKernelGGL(k_transpose, dim3(16, 8, 8), dim3(256), 0, stream, x, xT);
    hipLaunchKernelGGL(k_gemm_qk, dim3(512), dim3(256), 0, stream,
                       xT, wqb, wkb, bq, bk, qb, kb);
    hipLaunchKernelGGL(k_gemm_max, dim3(512), dim3(256), 0, stream, qb, kb, Mout);
    hipLaunchKernelGGL(k_softmax, dim3(8), dim3(256), 0, stream, Mout, wsm);
    hipLaunchKernelGGL(k_reduce_y, dim3(512), dim3(256), 0, stream, x, wsm, yv);
    hipLaunchKernelGGL(k_proto, dim3(512), dim3(64), 0, stream, W6, b6, yv, proto);
    hipLaunchKernelGGL(k_final, dim3(4096), dim3(256), 0, stream, x, proto, out);
}

// Round 2
// 125.891 us; speedup vs baseline: 1.1076x; 1.1076x over previous
//
#include <hip/hip_runtime.h>
#include <hip/hip_bf16.h>

typedef __bf16 bf16_t;
typedef __bf16 bf16x8 __attribute__((ext_vector_type(8)));
typedef float f32x4 __attribute__((ext_vector_type(4)));

#define B_   8
#define C_   512
#define HW_  1024
#define NPIX 8192

// ---- async global->LDS (16B per lane) ----
typedef __attribute__((address_space(3))) void lds_vp;
typedef const __attribute__((address_space(1))) void gbl_vp;
__device__ __forceinline__ void gload_lds16(const void* g, void* l) {
    __builtin_amdgcn_global_load_lds((gbl_vp*)g, (lds_vp*)l, 16, 0, 0);
}

// Stage a 128x64 bf16 tile (row-major, ld=ldk) into LDS [128][64] linearly.
__device__ __forceinline__ void stage128x64(const bf16_t* __restrict__ g, int ldk,
                                            bf16_t* lds, int tid) {
    int w64 = tid & ~63;
#pragma unroll
    for (int s = 0; s < 4; ++s) {
        int u = s * 256 + tid;
        const bf16_t* src = g + (size_t)(u >> 3) * ldk + (u & 7) * 8;
        gload_lds16((const void*)src, (void*)(lds + (size_t)(s * 256 + w64) * 8));
    }
}

// ---- K1a: convert weights to bf16 ----
__global__ void k_cvt_w(const float* __restrict__ Wq, const float* __restrict__ Wk,
                        bf16_t* __restrict__ wq, bf16_t* __restrict__ wk) {
    int i = blockIdx.x * 256 + threadIdx.x;
    wq[i] = (bf16_t)Wq[i];
    wk[i] = (bf16_t)Wk[i];
}

// ---- K1b: x [B,C,HW] f32 -> xT [B*HW, C] bf16 ----
__global__ void k_transpose(const float* __restrict__ x, bf16_t* __restrict__ xT) {
    __shared__ bf16_t tile[64 * 66];
    int p0 = blockIdx.x * 64, c0 = blockIdx.y * 64, b = blockIdx.z;
    int t = threadIdx.x;
#pragma unroll
    for (int s = 0; s < 16; ++s) {
        int u = s * 256 + t;
        int cr = u >> 6, pc = u & 63;
        tile[cr * 66 + pc] = (bf16_t)x[((size_t)(b * C_ + c0 + cr)) * HW_ + p0 + pc];
    }
    __syncthreads();
#pragma unroll
    for (int s = 0; s < 16; ++s) {
        int u = s * 256 + t;
        int pr = u >> 6, cc = u & 63;
        xT[((size_t)(b * HW_ + p0 + pr)) * C_ + c0 + cc] = tile[cc * 66 + pr];
    }
}

// ---- K2: q/k projection GEMM (m97 structure, 128x128 tiles) ----
__launch_bounds__(256, 2)
__global__ void k_gemm_qk(const bf16_t* __restrict__ xT,
                          const bf16_t* __restrict__ wq, const bf16_t* __restrict__ wk,
                          const float* __restrict__ bq, const float* __restrict__ bk,
                          bf16_t* __restrict__ qo, bf16_t* __restrict__ ko) {
    __shared__ bf16_t As[128 * 64];
    __shared__ bf16_t Bs[128 * 64];
    int bid = blockIdx.x;
    int mtile = bid >> 3;
    int nt = bid & 7;
    const bf16_t* wsel = (nt < 4) ? wq : wk;
    const float*  bsel = (nt < 4) ? bq : bk;
    bf16_t*       osel = (nt < 4) ? qo : ko;
    int nb = (nt & 3) * 128;
    int i0 = mtile * 128;
    int tid = threadIdx.x;
    int lane = tid & 63, w = tid >> 6;
    int wr = w >> 1, wc = w & 1, lr = lane & 15, lg = lane >> 4;

    f32x4 acc[4][4];
#pragma unroll
    for (int mi = 0; mi < 4; ++mi)
#pragma unroll
        for (int ni = 0; ni < 4; ++ni)
#pragma unroll
            for (int r = 0; r < 4; ++r) acc[mi][ni][r] = 0.f;

    for (int kt = 0; kt < 8; ++kt) {
        int k0 = kt * 64;
        stage128x64(xT + (size_t)i0 * 512 + k0, 512, As, tid);
        stage128x64(wsel + (size_t)nb * 512 + k0, 512, Bs, tid);
        __syncthreads();
#pragma unroll
        for (int kk = 0; kk < 2; ++kk) {
            bf16x8 af[4], bfr[4];
#pragma unroll
            for (int mi = 0; mi < 4; ++mi)
                af[mi] = *reinterpret_cast<const bf16x8*>(
                    &As[(wr * 64 + mi * 16 + lr) * 64 + kk * 32 + lg * 8]);
#pragma unroll
            for (int ni = 0; ni < 4; ++ni)
                bfr[ni] = *reinterpret_cast<const bf16x8*>(
                    &Bs[(wc * 64 + ni * 16 + lr) * 64 + kk * 32 + lg * 8]);
#pragma unroll
            for (int mi = 0; mi < 4; ++mi)
#pragma unroll
                for (int ni = 0; ni < 4; ++ni)
                    acc[mi][ni] = __builtin_amdgcn_mfma_f32_16x16x32_bf16(
                        af[mi], bfr[ni], acc[mi][ni], 0, 0, 0);
        }
        __syncthreads();
    }
#pragma unroll
    for (int ni = 0; ni < 4; ++ni) {
        int col = nb + wc * 64 + ni * 16 + lr;
        float bias = bsel[col];
#pragma unroll
        for (int mi = 0; mi < 4; ++mi) {
            int rowb = i0 + wr * 64 + mi * 16 + lg * 4;
#pragma unroll
            for (int r = 0; r < 4; ++r)
                osel[(size_t)(rowb + r) * 512 + col] = (bf16_t)(acc[mi][ni][r] + bias);
        }
    }
}

// ---- K3: 256x256 8-phase score GEMM + per-col-chunk max ----
// Regions: A(d,kk)=[256 rows][32 k] swizzled; B(d,kk) same. 2 dbuf.
// Row-pair interleave: elem (r,c) at byte (r>>1)*128 + slot*16 + (c&7)*2,
// slot = ((c>>3)*2 + (r&1)) ^ ((r>>1)&7).  (conflict-free ds_read_b128)

#define STAGE_A(D, KK, T)                                                          \
    gload_lds16((const void*)(q + srcA0 + (T) * 64 + (KK) * 32),                   \
                (void*)(lds + ((D) * 2 + (KK)) * 8192 + ld0));                     \
    gload_lds16((const void*)(q + srcA1 + (T) * 64 + (KK) * 32),                   \
                (void*)(lds + ((D) * 2 + (KK)) * 8192 + ld1));

#define STAGE_B(D, KK, T)                                                          \
    gload_lds16((const void*)(kp + srcB0 + (T) * 64 + (KK) * 32),                  \
                (void*)(lds + 32768 + ((D) * 2 + (KK)) * 8192 + ld0));             \
    gload_lds16((const void*)(kp + srcB1 + (T) * 64 + (KK) * 32),                  \
                (void*)(lds + 32768 + ((D) * 2 + (KK)) * 8192 + ld1));

#define MFMA_PHASE(D, KK, NH, STAGE_STMT, VM_STMT)                                 \
    {                                                                              \
        const bf16_t* Ab = lds + ((D) * 2 + (KK)) * 8192;                          \
        const bf16_t* Bb = lds + 32768 + ((D) * 2 + (KK)) * 8192;                  \
        if ((NH) == 0) {                                                           \
            _Pragma("unroll")                                                      \
            for (int mi = 0; mi < 8; ++mi)                                         \
                af[mi] = *(const bf16x8*)(Ab + aoff + mi * 512);                   \
            bf[0] = *(const bf16x8*)(Bb + boff + 0 * 512);                         \
            bf[1] = *(const bf16x8*)(Bb + boff + 1 * 512);                         \
        } else {                                                                   \
            bf[2] = *(const bf16x8*)(Bb + boff + 2 * 512);                         \
            bf[3] = *(const bf16x8*)(Bb + boff + 3 * 512);                         \
        }                                                                          \
        STAGE_STMT;                                                                \
        __builtin_amdgcn_s_barrier();                                              \
        asm volatile("s_waitcnt lgkmcnt(0)" ::: "memory");                         \
        __builtin_amdgcn_sched_barrier(0);                                         \
        __builtin_amdgcn_s_setprio(1);                                             \
        _Pragma("unroll")                                                          \
        for (int mi = 0; mi < 8; ++mi) {                                           \
            acc[mi][(NH) * 2 + 0] = __builtin_amdgcn_mfma_f32_16x16x32_bf16(       \
                af[mi], bf[(NH) * 2 + 0], acc[mi][(NH) * 2 + 0], 0, 0, 0);         \
            acc[mi][(NH) * 2 + 1] = __builtin_amdgcn_mfma_f32_16x16x32_bf16(       \
                af[mi], bf[(NH) * 2 + 1], acc[mi][(NH) * 2 + 1], 0, 0, 0);         \
        }                                                                          \
        __builtin_amdgcn_s_setprio(0);                                             \
        VM_STMT;                                                                   \
        __builtin_amdgcn_s_barrier();                                              \
    }

__global__ __launch_bounds__(512, 2)
void k_gemm_max8(const bf16_t* __restrict__ q, const bf16_t* __restrict__ kp,
                 float* __restrict__ Mout2) {
    __shared__ __align__(16) bf16_t lds[65536];   // 128 KiB
    int bid = blockIdx.x;
    int xcd = bid & 7, idx = bid >> 3;
    int mtile = xcd * 4 + (idx >> 5);   // each XCD owns 4 contiguous q panels
    int cblk = idx & 31;
    int i0 = mtile * 256, j0 = cblk * 256;
    int tid = threadIdx.x;
    int lane = tid & 63, w = tid >> 6;
    int wr = w >> 2, wc = w & 3;        // 2 x 4 wave grid
    int lr = lane & 15, lg = lane >> 4;
    int rowh = lr >> 1;
    int sA = (lg * 2 + (lr & 1)) ^ (rowh & 7);
    int aoff = (wr * 64 + rowh) * 64 + sA * 8;
    int boff = (wc * 32 + rowh) * 64 + sA * 8;

    // staging precompute (2 passes of 512 threads x 16B per half-region)
    int s0 = (tid & 7) ^ ((tid >> 3) & 7);
    int r0 = (tid >> 3) * 2 + (s0 & 1);
    size_t srcA0 = (size_t)(i0 + r0) * 512 + (s0 >> 1) * 8;
    size_t srcA1 = srcA0 + (size_t)128 * 512;
    size_t srcB0 = (size_t)(j0 + r0) * 512 + (s0 >> 1) * 8;
    size_t srcB1 = srcB0 + (size_t)128 * 512;
    int ld0 = (tid & ~63) * 8, ld1 = (512 + (tid & ~63)) * 8;

    f32x4 acc[8][4];
    bf16x8 af[8], bf[4];
#pragma unroll
    for (int mi = 0; mi < 8; ++mi)
#pragma unroll
        for (int ni = 0; ni < 4; ++ni)
#pragma unroll
            for (int r = 0; r < 4; ++r) acc[mi][ni][r] = 0.f;

    // prologue: tile0 -> dbuf0 (4 regions), tile1 -> dbuf1 (A_k0,B_k0,A_k1)
    STAGE_A(0, 0, 0) STAGE_B(0, 0, 0) STAGE_A(0, 1, 0) STAGE_B(0, 1, 0)
    STAGE_A(1, 0, 1) STAGE_B(1, 0, 1) STAGE_A(1, 1, 1)
    asm volatile("s_waitcnt vmcnt(6)" ::: "memory");
    __builtin_amdgcn_s_barrier();

#pragma unroll
    for (int i = 0; i < 4; ++i) {
        const int t1 = 2 * i + 1, t2 = 2 * i + 2, t3 = 2 * i + 3;
        // ph1: compute tile 2i (d0,k0,nh0); stage B(1,1) of tile 2i+1
        MFMA_PHASE(0, 0, 0, { STAGE_B(1, 1, t1) }, {})
        // ph2
        MFMA_PHASE(0, 0, 1, { if (i < 3) { STAGE_A(0, 0, t2) } }, {})
        // ph3
        MFMA_PHASE(0, 1, 0, { if (i < 3) { STAGE_B(0, 0, t2) } }, {})
        // ph4 (+vmcnt: force tile 2i+1 landed)
        MFMA_PHASE(0, 1, 1, { if (i < 3) { STAGE_A(0, 1, t2) } },
                   { if (i < 3) { asm volatile("s_waitcnt vmcnt(6)" ::: "memory"); }
                     else       { asm volatile("s_waitcnt vmcnt(0)" ::: "memory"); } })
        // ph5: compute tile 2i+1 (d1,k0,nh0)
        MFMA_PHASE(1, 0, 0, { if (i < 3) { STAGE_B(0, 1, t2) } }, {})
        // ph6
        MFMA_PHASE(1, 0, 1, { if (i < 3) { STAGE_A(1, 0, t3) } }, {})
        // ph7
        MFMA_PHASE(1, 1, 0, { if (i < 3) { STAGE_B(1, 0, t3) } }, {})
        // ph8 (+vmcnt: force tile 2i+2 landed)
        MFMA_PHASE(1, 1, 1, { if (i < 3) { STAGE_A(1, 1, t3) } },
                   { if (i < 3) { asm volatile("s_waitcnt vmcnt(6)" ::: "memory"); } })
    }

    // epilogue: per-row max over this block's 256 cols
    float rm[8][4];
#pragma unroll
    for (int mi = 0; mi < 8; ++mi)
#pragma unroll
        for (int r = 0; r < 4; ++r) {
            float v = fmaxf(fmaxf(acc[mi][0][r], acc[mi][1][r]),
                            fmaxf(acc[mi][2][r], acc[mi][3][r]));
#pragma unroll
            for (int off = 1; off < 16; off <<= 1) v = fmaxf(v, __shfl_xor(v, off));
            rm[mi][r] = v;
        }
    float* sm = (float*)lds;
    if (lr == 0) {
#pragma unroll
        for (int mi = 0; mi < 8; ++mi)
#pragma unroll
            for (int r = 0; r < 4; ++r)
                sm[wc * 256 + wr * 128 + mi * 16 + lg * 4 + r] = rm[mi][r];
    }
    __syncthreads();
    if (tid < 256) {
        float v = fmaxf(fmaxf(sm[tid], sm[256 + tid]),
                        fmaxf(sm[512 + tid], sm[768 + tid]));
        Mout2[(size_t)(i0 + tid) * 32 + cblk] = v;
    }
}

// ---- K4: fold 4 col-chunk maxes per image, mean over images, softmax ----
__global__ void k_softmax(const float* __restrict__ Mout2, float* __restrict__ wsm) {
    int b = blockIdx.x;
    int t = threadIdx.x;
    __shared__ float red[16];
    const float scale = 0.044194173824159216f;  // 1/sqrt(512)
    float s[4];
#pragma unroll
    for (int i = 0; i < 4; ++i) {
        int p = t + i * 256;
        const float4* row = (const float4*)&Mout2[(size_t)(b * 1024 + p) * 32];
        float acc = 0.f;
#pragma unroll
        for (int j = 0; j < 8; ++j) {
            float4 v = row[j];
            acc += fmaxf(fmaxf(v.x, v.y), fmaxf(v.z, v.w));
        }
        s[i] = acc * (scale / 8.0f);
    }
    float m = fmaxf(fmaxf(s[0], s[1]), fmaxf(s[2], s[3]));
#pragma unroll
    for (int off = 1; off < 64; off <<= 1) m = fmaxf(m, __shfl_xor(m, off));
    if ((t & 63) == 0) red[t >> 6] = m;
    __syncthreads();
    float m4 = fmaxf(fmaxf(red[0], red[1]), fmaxf(red[2], red[3]));
    float e[4], sum = 0.f;
#pragma unroll
    for (int i = 0; i < 4; ++i) { e[i] = __expf(s[i] - m4); sum += e[i]; }
#pragma unroll
    for (int off = 1; off < 64; off <<= 1) sum += __shfl_xor(sum, off);
    if ((t & 63) == 0) red[8 + (t >> 6)] = sum;
    __syncthreads();
    float tot = red[8] + red[9] + red[10] + red[11];
    float inv = 1.0f / tot;
#pragma unroll
    for (int i = 0; i < 4; ++i) wsm[b * 1024 + t + i * 256] = e[i] * inv;
}

// ---- K5: y[c] = mean_{b,p} x[b,c,p] * w[b,p] ----
__global__ void k_reduce_y(const float* __restrict__ x, const float* __restrict__ wsm,
                           float* __restrict__ y) {
    int c = blockIdx.x;
    int t = threadIdx.x;
    float acc = 0.f;
    for (int b = 0; b < 8; ++b) {
        const float* xb = x + ((size_t)(b * C_ + c)) * HW_;
        const float* wb = wsm + b * HW_;
#pragma unroll
        for (int i = 0; i < 4; ++i) {
            int p = t + i * 256;
            acc += xb[p] * wb[p];
        }
    }
#pragma unroll
    for (int off = 1; off < 64; off <<= 1) acc += __shfl_xor(acc, off);
    __shared__ float red[4];
    if ((t & 63) == 0) red[t >> 6] = acc;
    __syncthreads();
    if (t == 0) y[c] = (red[0] + red[1] + red[2] + red[3]) * (1.0f / 8192.0f);
}

// ---- K6: x_proto[d] = W6[d,:] . y + b6[d] ----
__global__ void k_proto(const float* __restrict__ W6, const float* __restrict__ b6,
                        const float* __restrict__ y, float* __restrict__ proto) {
    int d = blockIdx.x;
    int lane = threadIdx.x;
    float acc = 0.f;
#pragma unroll
    for (int i = 0; i < 8; ++i)
        acc += W6[(size_t)d * C_ + lane + i * 64] * y[lane + i * 64];
#pragma unroll
    for (int off = 1; off < 64; off <<= 1) acc += __shfl_xor(acc, off);
    if (lane == 0) proto[d] = acc + b6[d];
}

// ---- K7: out = x * proto[c] ----
__global__ void k_final(const float* __restrict__ x, const float* __restrict__ proto,
                        float* __restrict__ out) {
    int idx = blockIdx.x * 256 + threadIdx.x;
    float4 v = ((const float4*)x)[idx];
    int c = (idx >> 8) & 511;
    float p = proto[c];
    v.x *= p; v.y *= p; v.z *= p; v.w *= p;
    ((float4*)out)[idx] = v;
}

extern "C" void kernel_launch(void* const* d_in, const int* in_sizes, int n_in,
                              void* d_out, int out_size, void* d_ws, size_t ws_size,
                              hipStream_t stream) {
    const float* x  = (const float*)d_in[0];
    const float* Wq = (const float*)d_in[1];
    const float* bq = (const float*)d_in[2];
    const float* Wk = (const float*)d_in[3];
    const float* bk = (const float*)d_in[4];
    const float* W6 = (const float*)d_in[5];
    const float* b6 = (const float*)d_in[6];
    float* out = (float*)d_out;

    char* ws = (char*)d_ws;
    bf16_t* xT    = (bf16_t*)(ws);                 // 8.4 MB (dead after k_gemm_qk)
    float*  Mout2 = (float*)(ws);                  // 8192*32*4 = 1 MB, aliases xT
    bf16_t* wqb   = (bf16_t*)(ws + 8388608);
    bf16_t* wkb   = (bf16_t*)(ws + 8912896);
    bf16_t* qb    = (bf16_t*)(ws + 9437184);
    bf16_t* kb    = (bf16_t*)(ws + 17825792);
    float*  wsm   = (float*)(ws + 26476544);
    float*  yv    = (float*)(ws + 26509312);
    float*  proto = (float*)(ws + 26511360);

    hipLaunchKernelGGL(k_cvt_w, dim3(1024), dim3(256), 0, stream, Wq, Wk, wqb, wkb);
    hipLaunchKernelGGL(k_transpose, dim3(16, 8, 8), dim3(256), 0, stream, x, xT);
    hipLaunchKernelGGL(k_gemm_qk, dim3(512), dim3(256), 0, stream,
                       xT, wqb, wkb, bq, bk, qb, kb);
    hipLaunchKernelGGL(k_gemm_max8, dim3(1024), dim3(512), 0, stream, qb, kb, Mout2);
    hipLaunchKernelGGL(k_softmax, dim3(8), dim3(256), 0, stream, Mout2, wsm);
    hipLaunchKernelGGL(k_reduce_y, dim3(512), dim3(256), 0, stream, x, wsm, yv);
    hipLaunchKernelGGL(k_proto, dim3(512), dim3(64), 0, stream, W6, b6, yv, proto);
    hipLaunchKernelGGL(k_final, dim3(4096), dim3(256), 0, stream, x, proto, out);
}

// Round 3
// 110.338 us; speedup vs baseline: 1.2637x; 1.1410x over previous
//
#include <hip/hip_runtime.h>
#include <hip/hip_bf16.h>

typedef __bf16 bf16_t;
typedef __bf16 bf16x8 __attribute__((ext_vector_type(8)));
typedef float f32x4 __attribute__((ext_vector_type(4)));

#define B_   8
#define C_   512
#define HW_  1024
#define NPIX 8192

// ---- async global->LDS (16B per lane) ----
typedef __attribute__((address_space(3))) void lds_vp;
typedef const __attribute__((address_space(1))) void gbl_vp;
__device__ __forceinline__ void gload_lds16(const void* g, void* l) {
    __builtin_amdgcn_global_load_lds((gbl_vp*)g, (lds_vp*)l, 16, 0, 0);
}

// Stage a 128x64 bf16 tile (row-major, ld=ldk) into LDS [128][64] linearly.
__device__ __forceinline__ void stage128x64(const bf16_t* __restrict__ g, int ldk,
                                            bf16_t* lds, int tid) {
    int w64 = tid & ~63;
#pragma unroll
    for (int s = 0; s < 4; ++s) {
        int u = s * 256 + tid;
        const bf16_t* src = g + (size_t)(u >> 3) * ldk + (u & 7) * 8;
        gload_lds16((const void*)src, (void*)(lds + (size_t)(s * 256 + w64) * 8));
    }
}

// ---- K1a: convert weights to bf16 ----
__global__ void k_cvt_w(const float* __restrict__ Wq, const float* __restrict__ Wk,
                        bf16_t* __restrict__ wq, bf16_t* __restrict__ wk) {
    int i = blockIdx.x * 256 + threadIdx.x;
    wq[i] = (bf16_t)Wq[i];
    wk[i] = (bf16_t)Wk[i];
}

// ---- K1b: x [B,C,HW] f32 -> xT [B*HW, C] bf16 ----
__global__ void k_transpose(const float* __restrict__ x, bf16_t* __restrict__ xT) {
    __shared__ bf16_t tile[64 * 66];
    int p0 = blockIdx.x * 64, c0 = blockIdx.y * 64, b = blockIdx.z;
    int t = threadIdx.x;
#pragma unroll
    for (int s = 0; s < 16; ++s) {
        int u = s * 256 + t;
        int cr = u >> 6, pc = u & 63;
        tile[cr * 66 + pc] = (bf16_t)x[((size_t)(b * C_ + c0 + cr)) * HW_ + p0 + pc];
    }
    __syncthreads();
#pragma unroll
    for (int s = 0; s < 16; ++s) {
        int u = s * 256 + t;
        int pr = u >> 6, cc = u & 63;
        xT[((size_t)(b * HW_ + p0 + pr)) * C_ + c0 + cc] = tile[cc * 66 + pr];
    }
}

// ---- K2: q/k projection GEMM (m97 structure, 128x128 tiles) ----
__launch_bounds__(256, 2)
__global__ void k_gemm_qk(const bf16_t* __restrict__ xT,
                          const bf16_t* __restrict__ wq, const bf16_t* __restrict__ wk,
                          const float* __restrict__ bq, const float* __restrict__ bk,
                          bf16_t* __restrict__ qo, bf16_t* __restrict__ ko) {
    __shared__ bf16_t As[128 * 64];
    __shared__ bf16_t Bs[128 * 64];
    int bid = blockIdx.x;
    int mtile = bid >> 3;
    int nt = bid & 7;
    const bf16_t* wsel = (nt < 4) ? wq : wk;
    const float*  bsel = (nt < 4) ? bq : bk;
    bf16_t*       osel = (nt < 4) ? qo : ko;
    int nb = (nt & 3) * 128;
    int i0 = mtile * 128;
    int tid = threadIdx.x;
    int lane = tid & 63, w = tid >> 6;
    int wr = w >> 1, wc = w & 1, lr = lane & 15, lg = lane >> 4;

    f32x4 acc[4][4];
#pragma unroll
    for (int mi = 0; mi < 4; ++mi)
#pragma unroll
        for (int ni = 0; ni < 4; ++ni)
#pragma unroll
            for (int r = 0; r < 4; ++r) acc[mi][ni][r] = 0.f;

    for (int kt = 0; kt < 8; ++kt) {
        int k0 = kt * 64;
        stage128x64(xT + (size_t)i0 * 512 + k0, 512, As, tid);
        stage128x64(wsel + (size_t)nb * 512 + k0, 512, Bs, tid);
        __syncthreads();
#pragma unroll
        for (int kk = 0; kk < 2; ++kk) {
            bf16x8 af[4], bfr[4];
#pragma unroll
            for (int mi = 0; mi < 4; ++mi)
                af[mi] = *reinterpret_cast<const bf16x8*>(
                    &As[(wr * 64 + mi * 16 + lr) * 64 + kk * 32 + lg * 8]);
#pragma unroll
            for (int ni = 0; ni < 4; ++ni)
                bfr[ni] = *reinterpret_cast<const bf16x8*>(
                    &Bs[(wc * 64 + ni * 16 + lr) * 64 + kk * 32 + lg * 8]);
#pragma unroll
            for (int mi = 0; mi < 4; ++mi)
#pragma unroll
                for (int ni = 0; ni < 4; ++ni)
                    acc[mi][ni] = __builtin_amdgcn_mfma_f32_16x16x32_bf16(
                        af[mi], bfr[ni], acc[mi][ni], 0, 0, 0);
        }
        __syncthreads();
    }
#pragma unroll
    for (int ni = 0; ni < 4; ++ni) {
        int col = nb + wc * 64 + ni * 16 + lr;
        float bias = bsel[col];
#pragma unroll
        for (int mi = 0; mi < 4; ++mi) {
            int rowb = i0 + wr * 64 + mi * 16 + lg * 4;
#pragma unroll
            for (int r = 0; r < 4; ++r)
                osel[(size_t)(rowb + r) * 512 + col] = (bf16_t)(acc[mi][ni][r] + bias);
        }
    }
}

// ---- K3: score GEMM + per-key-image max ----
// 256 blocks = (q-panel of 256 rows) x (key image). Per block: 4 n-chunks of
// 256 key pixels, K=512 each; 32 K-tiles in one continuous 8-phase pipeline.
// LDS regions (D*2+KK), A at 0, B at +32768 elems; each region [256r][32k]
// swizzled: elem (r,c) at byte (r>>1)*128 + slot*16 + (c&7)*2,
// slot = ((c>>3)*2 + (r&1)) ^ ((r>>1)&7).

#define STAGE_AR(REG, OFF)                                                         \
    gload_lds16((const void*)(q + srcA0 + (OFF)),                                  \
                (void*)(lds + (REG) * 8192 + ld0));                                \
    gload_lds16((const void*)(q + srcA1 + (OFF)),                                  \
                (void*)(lds + (REG) * 8192 + ld1));

#define STAGE_BR(REG, OFF)                                                         \
    gload_lds16((const void*)(kb + srcB0 + (OFF)),                                 \
                (void*)(lds + 32768 + (REG) * 8192 + ld0));                        \
    gload_lds16((const void*)(kb + srcB1 + (OFF)),                                 \
                (void*)(lds + 32768 + (REG) * 8192 + ld1));

#define PHASE(REGI, MH, STAGE_STMT, VM_STMT)                                       \
    {                                                                              \
        const bf16_t* Ab = lds + (REGI) * 8192;                                    \
        const bf16_t* Bb = lds + 32768 + (REGI) * 8192;                            \
        _Pragma("unroll")                                                          \
        for (int mi = 0; mi < 4; ++mi)                                             \
            af[mi] = *(const bf16x8*)(Ab + aoff + ((MH) * 4 + mi) * 512);          \
        if ((MH) == 0) {                                                           \
            _Pragma("unroll")                                                      \
            for (int ni = 0; ni < 4; ++ni)                                         \
                bf[ni] = *(const bf16x8*)(Bb + boff + ni * 512);                   \
        }                                                                          \
        STAGE_STMT;                                                                \
        __builtin_amdgcn_s_barrier();                                              \
        asm volatile("s_waitcnt lgkmcnt(0)" ::: "memory");                         \
        __builtin_amdgcn_sched_barrier(0);                                         \
        __builtin_amdgcn_s_setprio(1);                                             \
        _Pragma("unroll")                                                          \
        for (int mi = 0; mi < 4; ++mi)                                             \
            _Pragma("unroll")                                                      \
            for (int ni = 0; ni < 4; ++ni)                                         \
                acc[(MH) * 4 + mi][ni] = __builtin_amdgcn_mfma_f32_16x16x32_bf16(  \
                    af[mi], bf[ni], acc[(MH) * 4 + mi][ni], 0, 0, 0);              \
        __builtin_amdgcn_s_setprio(0);                                             \
        VM_STMT;                                                                   \
        __builtin_amdgcn_s_barrier();                                              \
    }

__global__ __launch_bounds__(512, 2)
void k_gemm_max8(const bf16_t* __restrict__ q, const bf16_t* __restrict__ kp,
                 float* __restrict__ Mout) {
    __shared__ __align__(16) bf16_t lds[65536];   // 128 KiB
    int bid = blockIdx.x;           // 256 blocks
    int img = bid & 7;              // XCD-local key image
    int qp = bid >> 3;              // 0..31
    int i0 = qp * 256;
    const bf16_t* kb = kp + (size_t)img * HW_ * C_;
    int tid = threadIdx.x;
    int lane = tid & 63, w = tid >> 6;
    int wr = w >> 2, wc = w & 3;    // 2 x 4 wave grid
    int lr = lane & 15, lg = lane >> 4;
    int rowh = lr >> 1;
    int sA = (lg * 2 + (lr & 1)) ^ (rowh & 7);
    int aoff = (wr * 64 + rowh) * 64 + sA * 8;
    int boff = (wc * 32 + rowh) * 64 + sA * 8;

    // staging precompute (inverse-swizzled global source, linear LDS dest)
    int s0 = (tid & 7) ^ ((tid >> 3) & 7);
    int r0 = (tid >> 3) * 2 + (s0 & 1);
    size_t srcA0 = (size_t)(i0 + r0) * 512 + (s0 >> 1) * 8;
    size_t srcA1 = srcA0 + (size_t)128 * 512;
    size_t srcB0 = (size_t)r0 * 512 + (s0 >> 1) * 8;
    size_t srcB1 = srcB0 + (size_t)128 * 512;
    int ld0 = (tid & ~63) * 8, ld1 = (512 + (tid & ~63)) * 8;

    f32x4 acc[8][4];
    bf16x8 af[4], bf[4];
    float rm[8][4];
#pragma unroll
    for (int mi = 0; mi < 8; ++mi)
#pragma unroll
        for (int ni = 0; ni < 4; ++ni)
#pragma unroll
            for (int r = 0; r < 4; ++r) acc[mi][ni][r] = 0.f;
#pragma unroll
    for (int mi = 0; mi < 8; ++mi)
#pragma unroll
        for (int r = 0; r < 4; ++r) rm[mi][r] = -3.4e38f;

    // prologue: tile0 -> regions 0,1; tile1 -> regions 2,3 (minus A11)
    STAGE_BR(0, 0) STAGE_AR(0, 0) STAGE_BR(1, 32) STAGE_AR(1, 32)
    STAGE_BR(2, 64) STAGE_AR(2, 64) STAGE_BR(3, 96)
    asm volatile("s_waitcnt vmcnt(6)" ::: "memory");
    __builtin_amdgcn_s_barrier();

    for (int i = 0; i < 16; ++i) {
        int t1 = 2 * i + 1, t2 = t1 + 1, t3 = t1 + 2;
        int a1 = (t1 & 7) * 64, a2 = (t2 & 7) * 64, a3 = (t3 & 7) * 64;
        int b2 = ((t2 >> 3) << 17) + a2, b3 = ((t3 >> 3) << 17) + a3;
        bool s = (i < 15);
        // ph1: compute D0/KK0/mi0-3 ; stage A(1,1)@t1
        PHASE(0, 0, { STAGE_AR(3, a1 + 32) }, {})
        // ph2: D0/KK0/mi4-7 ; stage B(0,0)@t2
        PHASE(0, 1, { if (s) { STAGE_BR(0, b2) } }, {})
        // ph3: D0/KK1/mi0-3 ; stage A(0,0)@t2
        PHASE(1, 0, { if (s) { STAGE_AR(0, a2) } }, {})
        // ph4: D0/KK1/mi4-7 ; stage B(0,1)@t2 ; vmcnt
        PHASE(1, 1, { if (s) { STAGE_BR(1, b2 + 32) } },
              { if (s) { asm volatile("s_waitcnt vmcnt(6)" ::: "memory"); }
                else   { asm volatile("s_waitcnt vmcnt(0)" ::: "memory"); } })
        // ph5: D1/KK0/mi0-3 ; stage A(0,1)@t2
        PHASE(2, 0, { if (s) { STAGE_AR(1, a2 + 32) } }, {})
        // ph6: D1/KK0/mi4-7 ; stage B(1,0)@t3
        PHASE(2, 1, { if (s) { STAGE_BR(2, b3) } }, {})
        // ph7: D1/KK1/mi0-3 ; stage A(1,0)@t3
        PHASE(3, 0, { if (s) { STAGE_AR(2, a3) } }, {})
        // ph8: D1/KK1/mi4-7 ; stage B(1,1)@t3 ; vmcnt
        PHASE(3, 1, { if (s) { STAGE_BR(3, b3 + 32) } },
              { if (s) { asm volatile("s_waitcnt vmcnt(6)" ::: "memory"); } })
        if ((i & 3) == 3) {   // n-chunk complete: fold acc into rm, reset acc
#pragma unroll
            for (int mi = 0; mi < 8; ++mi)
#pragma unroll
                for (int r = 0; r < 4; ++r) {
                    float v = fmaxf(fmaxf(acc[mi][0][r], acc[mi][1][r]),
                                    fmaxf(acc[mi][2][r], acc[mi][3][r]));
                    rm[mi][r] = fmaxf(rm[mi][r], v);
#pragma unroll
                    for (int ni = 0; ni < 4; ++ni) acc[mi][ni][r] = 0.f;
                }
        }
    }

    // epilogue: reduce across 16 col-lanes, then across the 4 wc waves
#pragma unroll
    for (int mi = 0; mi < 8; ++mi)
#pragma unroll
        for (int r = 0; r < 4; ++r) {
            float v = rm[mi][r];
#pragma unroll
            for (int off = 1; off < 16; off <<= 1) v = fmaxf(v, __shfl_xor(v, off));
            rm[mi][r] = v;
        }
    float* sm = (float*)lds;
    if (lr == 0) {
#pragma unroll
        for (int mi = 0; mi < 8; ++mi)
#pragma unroll
            for (int r = 0; r < 4; ++r)
                sm[wc * 256 + wr * 128 + mi * 16 + lg * 4 + r] = rm[mi][r];
    }
    __syncthreads();
    if (tid < 256) {
        float v = fmaxf(fmaxf(sm[tid], sm[256 + tid]),
                        fmaxf(sm[512 + tid], sm[768 + tid]));
        Mout[(size_t)(i0 + tid) * 8 + img] = v;
    }
}

// ---- K4: mean over key images, scale, softmax per query image ----
__global__ void k_softmax(const float* __restrict__ Mout, float* __restrict__ wsm) {
    int b = blockIdx.x;
    int t = threadIdx.x;
    __shared__ float red[16];
    const float scale = 0.044194173824159216f;  // 1/sqrt(512)
    float s[4];
#pragma unroll
    for (int i = 0; i < 4; ++i) {
        int p = t + i * 256;
        const float* row = &Mout[(size_t)(b * 1024 + p) * 8];
        float acc = 0.f;
#pragma unroll
        for (int j = 0; j < 8; ++j) acc += row[j];
        s[i] = acc * (scale / 8.0f);
    }
    float m = fmaxf(fmaxf(s[0], s[1]), fmaxf(s[2], s[3]));
#pragma unroll
    for (int off = 1; off < 64; off <<= 1) m = fmaxf(m, __shfl_xor(m, off));
    if ((t & 63) == 0) red[t >> 6] = m;
    __syncthreads();
    float m4 = fmaxf(fmaxf(red[0], red[1]), fmaxf(red[2], red[3]));
    float e[4], sum = 0.f;
#pragma unroll
    for (int i = 0; i < 4; ++i) { e[i] = __expf(s[i] - m4); sum += e[i]; }
#pragma unroll
    for (int off = 1; off < 64; off <<= 1) sum += __shfl_xor(sum, off);
    if ((t & 63) == 0) red[8 + (t >> 6)] = sum;
    __syncthreads();
    float tot = red[8] + red[9] + red[10] + red[11];
    float inv = 1.0f / tot;
#pragma unroll
    for (int i = 0; i < 4; ++i) wsm[b * 1024 + t + i * 256] = e[i] * inv;
}

// ---- K5: y[c] = mean_{b,p} x[b,c,p] * w[b,p] ----
__global__ void k_reduce_y(const float* __restrict__ x, const float* __restrict__ wsm,
                           float* __restrict__ y) {
    int c = blockIdx.x;
    int t = threadIdx.x;
    float acc = 0.f;
    for (int b = 0; b < 8; ++b) {
        const float* xb = x + ((size_t)(b * C_ + c)) * HW_;
        const float* wb = wsm + b * HW_;
#pragma unroll
        for (int i = 0; i < 4; ++i) {
            int p = t + i * 256;
            acc += xb[p] * wb[p];
        }
    }
#pragma unroll
    for (int off = 1; off < 64; off <<= 1) acc += __shfl_xor(acc, off);
    __shared__ float red[4];
    if ((t & 63) == 0) red[t >> 6] = acc;
    __syncthreads();
    if (t == 0) y[c] = (red[0] + red[1] + red[2] + red[3]) * (1.0f / 8192.0f);
}

// ---- K6: x_proto[d] = W6[d,:] . y + b6[d] ----
__global__ void k_proto(const float* __restrict__ W6, const float* __restrict__ b6,
                        const float* __restrict__ y, float* __restrict__ proto) {
    int d = blockIdx.x;
    int lane = threadIdx.x;
    float acc = 0.f;
#pragma unroll
    for (int i = 0; i < 8; ++i)
        acc += W6[(size_t)d * C_ + lane + i * 64] * y[lane + i * 64];
#pragma unroll
    for (int off = 1; off < 64; off <<= 1) acc += __shfl_xor(acc, off);
    if (lane == 0) proto[d] = acc + b6[d];
}

// ---- K7: out = x * proto[c] ----
__global__ void k_final(const float* __restrict__ x, const float* __restrict__ proto,
                        float* __restrict__ out) {
    int idx = blockIdx.x * 256 + threadIdx.x;
    float4 v = ((const float4*)x)[idx];
    int c = (idx >> 8) & 511;
    float p = proto[c];
    v.x *= p; v.y *= p; v.z *= p; v.w *= p;
    ((float4*)out)[idx] = v;
}

extern "C" void kernel_launch(void* const* d_in, const int* in_sizes, int n_in,
                              void* d_out, int out_size, void* d_ws, size_t ws_size,
                              hipStream_t stream) {
    const float* x  = (const float*)d_in[0];
    const float* Wq = (const float*)d_in[1];
    const float* bq = (const float*)d_in[2];
    const float* Wk = (const float*)d_in[3];
    const float* bk = (const float*)d_in[4];
    const float* W6 = (const float*)d_in[5];
    const float* b6 = (const float*)d_in[6];
    float* out = (float*)d_out;

    char* ws = (char*)d_ws;
    bf16_t* xT    = (bf16_t*)(ws);                 // 8.4 MB (dead after k_gemm_qk)
    float*  Mout  = (float*)(ws);                  // 8192*8*4 = 256 KB, aliases xT
    bf16_t* wqb   = (bf16_t*)(ws + 8388608);
    bf16_t* wkb   = (bf16_t*)(ws + 8912896);
    bf16_t* qb    = (bf16_t*)(ws + 9437184);
    bf16_t* kb    = (bf16_t*)(ws + 17825792);
    float*  wsm   = (float*)(ws + 26476544);
    float*  yv    = (float*)(ws + 26509312);
    float*  proto = (float*)(ws + 26511360);

    hipLaunchKernelGGL(k_cvt_w, dim3(1024), dim3(256), 0, stream, Wq, Wk, wqb, wkb);
    hipLaunchKernelGGL(k_transpose, dim3(16, 8, 8), dim3(256), 0, stream, x, xT);
    hipLaunchKernelGGL(k_gemm_qk, dim3(512), dim3(256), 0, stream,
                       xT, wqb, wkb, bq, bk, qb, kb);
    hipLaunchKernelGGL(k_gemm_max8, dim3(256), dim3(512), 0, stream, qb, kb, Mout);
    hipLaunchKernelGGL(k_softmax, dim3(8), dim3(256), 0, stream, Mout, wsm);
    hipLaunchKernelGGL(k_reduce_y, dim3(512), dim3(256), 0, stream, x, wsm, yv);
    hipLaunchKernelGGL(k_proto, dim3(512), dim3(64), 0, stream, W6, b6, yv, proto);
    hipLaunchKernelGGL(k_final, dim3(4096), dim3(256), 0, stream, x, proto, out);
}

// Round 4
// 107.323 us; speedup vs baseline: 1.2992x; 1.0281x over previous
//
#include <hip/hip_runtime.h>
#include <hip/hip_bf16.h>

typedef __bf16 bf16_t;
typedef __bf16 bf16x8 __attribute__((ext_vector_type(8)));
typedef float f32x4 __attribute__((ext_vector_type(4)));

#define B_   8
#define C_   512
#define HW_  1024
#define NPIX 8192

// ---- async global->LDS (16B per lane) ----
typedef __attribute__((address_space(3))) void lds_vp;
typedef const __attribute__((address_space(1))) void gbl_vp;
__device__ __forceinline__ void gload_lds16(const void* g, void* l) {
    __builtin_amdgcn_global_load_lds((gbl_vp*)g, (lds_vp*)l, 16, 0, 0);
}

// Stage a 128x64 bf16 tile (row-major, ld=ldk) into LDS [128][64] linearly.
__device__ __forceinline__ void stage128x64(const bf16_t* __restrict__ g, int ldk,
                                            bf16_t* lds, int tid) {
    int w64 = tid & ~63;
#pragma unroll
    for (int s = 0; s < 4; ++s) {
        int u = s * 256 + tid;
        const bf16_t* src = g + (size_t)(u >> 3) * ldk + (u & 7) * 8;
        gload_lds16((const void*)src, (void*)(lds + (size_t)(s * 256 + w64) * 8));
    }
}

// ---- K1a: convert weights to bf16 ----
__global__ void k_cvt_w(const float* __restrict__ Wq, const float* __restrict__ Wk,
                        bf16_t* __restrict__ wq, bf16_t* __restrict__ wk) {
    int i = blockIdx.x * 256 + threadIdx.x;
    wq[i] = (bf16_t)Wq[i];
    wk[i] = (bf16_t)Wk[i];
}

// ---- K1b: x [B,C,HW] f32 -> xT [B*HW, C] bf16 ----
__global__ void k_transpose(const float* __restrict__ x, bf16_t* __restrict__ xT) {
    __shared__ bf16_t tile[64 * 66];
    int p0 = blockIdx.x * 64, c0 = blockIdx.y * 64, b = blockIdx.z;
    int t = threadIdx.x;
#pragma unroll
    for (int s = 0; s < 16; ++s) {
        int u = s * 256 + t;
        int cr = u >> 6, pc = u & 63;
        tile[cr * 66 + pc] = (bf16_t)x[((size_t)(b * C_ + c0 + cr)) * HW_ + p0 + pc];
    }
    __syncthreads();
#pragma unroll
    for (int s = 0; s < 16; ++s) {
        int u = s * 256 + t;
        int pr = u >> 6, cc = u & 63;
        xT[((size_t)(b * HW_ + p0 + pr)) * C_ + c0 + cc] = tile[cc * 66 + pr];
    }
}

// ---- K2: q/k projection GEMM (m97 structure, 128x128 tiles) ----
__launch_bounds__(256, 2)
__global__ void k_gemm_qk(const bf16_t* __restrict__ xT,
                          const bf16_t* __restrict__ wq, const bf16_t* __restrict__ wk,
                          const float* __restrict__ bq, const float* __restrict__ bk,
                          bf16_t* __restrict__ qo, bf16_t* __restrict__ ko) {
    __shared__ bf16_t As[128 * 64];
    __shared__ bf16_t Bs[128 * 64];
    int bid = blockIdx.x;
    int mtile = bid >> 3;
    int nt = bid & 7;
    const bf16_t* wsel = (nt < 4) ? wq : wk;
    const float*  bsel = (nt < 4) ? bq : bk;
    bf16_t*       osel = (nt < 4) ? qo : ko;
    int nb = (nt & 3) * 128;
    int i0 = mtile * 128;
    int tid = threadIdx.x;
    int lane = tid & 63, w = tid >> 6;
    int wr = w >> 1, wc = w & 1, lr = lane & 15, lg = lane >> 4;

    f32x4 acc[4][4];
#pragma unroll
    for (int mi = 0; mi < 4; ++mi)
#pragma unroll
        for (int ni = 0; ni < 4; ++ni)
#pragma unroll
            for (int r = 0; r < 4; ++r) acc[mi][ni][r] = 0.f;

    for (int kt = 0; kt < 8; ++kt) {
        int k0 = kt * 64;
        stage128x64(xT + (size_t)i0 * 512 + k0, 512, As, tid);
        stage128x64(wsel + (size_t)nb * 512 + k0, 512, Bs, tid);
        __syncthreads();
#pragma unroll
        for (int kk = 0; kk < 2; ++kk) {
            bf16x8 af[4], bfr[4];
#pragma unroll
            for (int mi = 0; mi < 4; ++mi)
                af[mi] = *reinterpret_cast<const bf16x8*>(
                    &As[(wr * 64 + mi * 16 + lr) * 64 + kk * 32 + lg * 8]);
#pragma unroll
            for (int ni = 0; ni < 4; ++ni)
                bfr[ni] = *reinterpret_cast<const bf16x8*>(
                    &Bs[(wc * 64 + ni * 16 + lr) * 64 + kk * 32 + lg * 8]);
#pragma unroll
            for (int mi = 0; mi < 4; ++mi)
#pragma unroll
                for (int ni = 0; ni < 4; ++ni)
                    acc[mi][ni] = __builtin_amdgcn_mfma_f32_16x16x32_bf16(
                        af[mi], bfr[ni], acc[mi][ni], 0, 0, 0);
        }
        __syncthreads();
    }
#pragma unroll
    for (int ni = 0; ni < 4; ++ni) {
        int col = nb + wc * 64 + ni * 16 + lr;
        float bias = bsel[col];
#pragma unroll
        for (int mi = 0; mi < 4; ++mi) {
            int rowb = i0 + wr * 64 + mi * 16 + lg * 4;
#pragma unroll
            for (int r = 0; r < 4; ++r)
                osel[(size_t)(rowb + r) * 512 + col] = (bf16_t)(acc[mi][ni][r] + bias);
        }
    }
}

// ---- K3: score GEMM + per-key-image max, m201-style st_16x32 LDS ----
// 256 blocks = (q-panel 256 rows) x (key image). 32 K-tiles (4 n-chunks x 8).
// 8 LDS regions of [128 rows][128 B]: A_rh{0,1} x dbuf2 at 0..65535,
// B_rh{0,1} x dbuf2 at 65536..131071. Swizzle: byte ^= ((row>>2)&1)<<5.
// Stage ledger (iter i: ta=2i d0, tb=2i+1 d1, tc=2i+2, td=2i+3):
//   ph1:A0d1(tb) ph2:B1d1(tb) ph3:A1d1(tb) ph4:B0d0(tc)+vmcnt(2)
//   ph5:A0d0(tc) ph6:B1d0(tc) ph7:A1d0(tc) ph8:B0d1(td)+vmcnt(2)
// Each region staged exactly one phase after its last read (WAR-safe);
// vmcnt(2) leaves only the newest stage in flight (RAW-safe).

#define STAGE_A(RH, D, T)                                                          \
    gload_lds16((const void*)(q + srcA + (size_t)((RH) * 128) * 512 +              \
                              ((T) & 7) * 64),                                     \
                (void*)(ldsb + (RH) * 32768 + (D) * 16384 + ldw));                 \
    gload_lds16((const void*)(q + srcA + (size_t)((RH) * 128 + 64) * 512 +         \
                              ((T) & 7) * 64),                                     \
                (void*)(ldsb + (RH) * 32768 + (D) * 16384 + 8192 + ldw));

#define STAGE_B(RH, D, T)                                                          \
    gload_lds16((const void*)(kb + srcB +                                          \
                              (size_t)(((T) >> 3) * 256 + (RH) * 128) * 512 +      \
                              ((T) & 7) * 64),                                     \
                (void*)(ldsb + 65536 + (RH) * 32768 + (D) * 16384 + ldw));         \
    gload_lds16((const void*)(kb + srcB +                                          \
                              (size_t)(((T) >> 3) * 256 + (RH) * 128 + 64) * 512 + \
                              ((T) & 7) * 64),                                     \
                (void*)(ldsb + 65536 + (RH) * 32768 + (D) * 16384 + 8192 + ldw));

#define PHASE(D, KH, MH, STAGE_STMT, VM_STMT)                                      \
    {                                                                              \
        const char* Ab = ldsb + wr * 32768 + (D) * 16384 + (KH) * 64;              \
        const char* Bb = ldsb + 65536 + (wc >> 1) * 32768 + (D) * 16384 +          \
                         (KH) * 64;                                                \
        _Pragma("unroll")                                                          \
        for (int mi = 0; mi < 4; ++mi)                                             \
            af[mi] = *(const bf16x8*)(Ab + aswz + ((MH) * 4 + mi) * 2048);         \
        if ((MH) == 0) {                                                           \
            _Pragma("unroll")                                                      \
            for (int ni = 0; ni < 4; ++ni)                                         \
                bf[ni] = *(const bf16x8*)(Bb + bswz + ni * 2048);                  \
        }                                                                          \
        STAGE_STMT;                                                                \
        __builtin_amdgcn_s_barrier();                                              \
        asm volatile("s_waitcnt lgkmcnt(0)" ::: "memory");                         \
        __builtin_amdgcn_sched_barrier(0);                                         \
        __builtin_amdgcn_s_setprio(1);                                             \
        _Pragma("unroll")                                                          \
        for (int mi = 0; mi < 4; ++mi)                                             \
            _Pragma("unroll")                                                      \
            for (int ni = 0; ni < 4; ++ni)                                         \
                acc[(MH) * 4 + mi][ni] = __builtin_amdgcn_mfma_f32_16x16x32_bf16(  \
                    af[mi], bf[ni], acc[(MH) * 4 + mi][ni], 0, 0, 0);              \
        __builtin_amdgcn_s_setprio(0);                                             \
        VM_STMT;                                                                   \
        __builtin_amdgcn_s_barrier();                                              \
    }

__global__ __launch_bounds__(512, 2)
void k_gemm_max8(const bf16_t* __restrict__ q, const bf16_t* __restrict__ kp,
                 float* __restrict__ Mout) {
    __shared__ __align__(16) bf16_t lds[65536];   // 128 KiB
    char* ldsb = (char*)lds;
    int bid = blockIdx.x;           // 256 blocks
    int img = bid & 7;              // XCD-local key image
    int qp = bid >> 3;              // 0..31
    int i0 = qp * 256;
    const bf16_t* kb = kp + (size_t)img * HW_ * C_;
    int tid = threadIdx.x;
    int lane = tid & 63, w = tid >> 6;
    int wr = w >> 2, wc = w & 3;    // 2 x 4 wave grid
    int lr = lane & 15, lg = lane >> 4;
    // read offsets (st_16x32: bank-bit5 ^= row-bit2 == lr-bit2, per-lane const)
    int kswz = (lg * 16) ^ ((lr & 4) << 3);
    int aswz = lr * 128 + kswz;
    int bswz = ((wc & 1) * 64 + lr) * 128 + kswz;

    // staging: thread t, pass p covers LDS byte p*8192+(t>>6)*1024+(t&63)*16;
    // inverse-swizzled source: row = p*64+(t>>6)*8+((t>>3)&7),
    // k = (t&7)*8 ^ ((t&32)>>1)
    int srow = ((tid >> 6) << 3) + ((tid >> 3) & 7);
    int sk = ((tid & 7) << 3) ^ ((tid & 32) >> 1);
    size_t srcA = (size_t)(i0 + srow) * 512 + sk;
    size_t srcB = (size_t)srow * 512 + sk;
    int ldw = (tid >> 6) * 1024;    // wave-uniform LDS byte base

    f32x4 acc[8][4];
    bf16x8 af[4], bf[4];
    float rm[8][4];
#pragma unroll
    for (int mi = 0; mi < 8; ++mi)
#pragma unroll
        for (int ni = 0; ni < 4; ++ni)
#pragma unroll
            for (int r = 0; r < 4; ++r) acc[mi][ni][r] = 0.f;
#pragma unroll
    for (int mi = 0; mi < 8; ++mi)
#pragma unroll
        for (int r = 0; r < 4; ++r) rm[mi][r] = -3.4e38f;

    // prologue: t0 all 4 regions (d0), t1 B0 (d1)
    STAGE_B(0, 0, 0) STAGE_A(0, 0, 0) STAGE_B(1, 0, 0) STAGE_A(1, 0, 0)
    STAGE_B(0, 1, 1)
    asm volatile("s_waitcnt vmcnt(2)" ::: "memory");
    __builtin_amdgcn_s_barrier();

    for (int i = 0; i < 16; ++i) {
        int tb = 2 * i + 1, tc = 2 * i + 2, td = 2 * i + 3;
        bool s = (i < 15);
        // ph1: ta kh0 m0-3 ; stage A0d1(tb)
        PHASE(0, 0, 0, { STAGE_A(0, 1, tb) }, {})
        // ph2: ta kh0 m4-7 ; stage B1d1(tb)
        PHASE(0, 0, 1, { STAGE_B(1, 1, tb) }, {})
        // ph3: ta kh1 m0-3 ; stage A1d1(tb)
        PHASE(0, 1, 0, { STAGE_A(1, 1, tb) }, {})
        // ph4: ta kh1 m4-7 ; stage B0d0(tc) ; vmcnt forces tb landed
        PHASE(0, 1, 1, { if (s) { STAGE_B(0, 0, tc) } },
              { if (s) { asm volatile("s_waitcnt vmcnt(2)" ::: "memory"); }
                else   { asm volatile("s_waitcnt vmcnt(0)" ::: "memory"); } })
        // ph5: tb kh0 m0-3 ; stage A0d0(tc)
        PHASE(1, 0, 0, { if (s) { STAGE_A(0, 0, tc) } }, {})
        // ph6: tb kh0 m4-7 ; stage B1d0(tc)
        PHASE(1, 0, 1, { if (s) { STAGE_B(1, 0, tc) } }, {})
        // ph7: tb kh1 m0-3 ; stage A1d0(tc)
        PHASE(1, 1, 0, { if (s) { STAGE_A(1, 0, tc) } }, {})
        // ph8: tb kh1 m4-7 ; stage B0d1(td) ; vmcnt forces tc landed
        PHASE(1, 1, 1, { if (s) { STAGE_B(0, 1, td) } },
              { if (s) { asm volatile("s_waitcnt vmcnt(2)" ::: "memory"); } })
        if ((i & 3) == 3) {   // n-chunk complete: fold acc into rm, reset acc
#pragma unroll
            for (int mi = 0; mi < 8; ++mi)
#pragma unroll
                for (int r = 0; r < 4; ++r) {
                    float v = fmaxf(fmaxf(acc[mi][0][r], acc[mi][1][r]),
                                    fmaxf(acc[mi][2][r], acc[mi][3][r]));
                    rm[mi][r] = fmaxf(rm[mi][r], v);
#pragma unroll
                    for (int ni = 0; ni < 4; ++ni) acc[mi][ni][r] = 0.f;
                }
        }
    }

    // epilogue: reduce across 16 col-lanes, then across the 4 wc waves
#pragma unroll
    for (int mi = 0; mi < 8; ++mi)
#pragma unroll
        for (int r = 0; r < 4; ++r) {
            float v = rm[mi][r];
#pragma unroll
            for (int off = 1; off < 16; off <<= 1) v = fmaxf(v, __shfl_xor(v, off));
            rm[mi][r] = v;
        }
    float* sm = (float*)lds;
    if (lr == 0) {
#pragma unroll
        for (int mi = 0; mi < 8; ++mi)
#pragma unroll
            for (int r = 0; r < 4; ++r)
                sm[wc * 256 + wr * 128 + mi * 16 + lg * 4 + r] = rm[mi][r];
    }
    __syncthreads();
    if (tid < 256) {
        float v = fmaxf(fmaxf(sm[tid], sm[256 + tid]),
                        fmaxf(sm[512 + tid], sm[768 + tid]));
        Mout[(size_t)(i0 + tid) * 8 + img] = v;
    }
}

// ---- K4: mean over key images, scale, softmax per query image ----
__global__ void k_softmax(const float* __restrict__ Mout, float* __restrict__ wsm) {
    int b = blockIdx.x;
    int t = threadIdx.x;
    __shared__ float red[16];
    const float scale = 0.044194173824159216f;  // 1/sqrt(512)
    float s[4];
#pragma unroll
    for (int i = 0; i < 4; ++i) {
        int p = t + i * 256;
        const float* row = &Mout[(size_t)(b * 1024 + p) * 8];
        float acc = 0.f;
#pragma unroll
        for (int j = 0; j < 8; ++j) acc += row[j];
        s[i] = acc * (scale / 8.0f);
    }
    float m = fmaxf(fmaxf(s[0], s[1]), fmaxf(s[2], s[3]));
#pragma unroll
    for (int off = 1; off < 64; off <<= 1) m = fmaxf(m, __shfl_xor(m, off));
    if ((t & 63) == 0) red[t >> 6] = m;
    __syncthreads();
    float m4 = fmaxf(fmaxf(red[0], red[1]), fmaxf(red[2], red[3]));
    float e[4], sum = 0.f;
#pragma unroll
    for (int i = 0; i < 4; ++i) { e[i] = __expf(s[i] - m4); sum += e[i]; }
#pragma unroll
    for (int off = 1; off < 64; off <<= 1) sum += __shfl_xor(sum, off);
    if ((t & 63) == 0) red[8 + (t >> 6)] = sum;
    __syncthreads();
    float tot = red[8] + red[9] + red[10] + red[11];
    float inv = 1.0f / tot;
#pragma unroll
    for (int i = 0; i < 4; ++i) wsm[b * 1024 + t + i * 256] = e[i] * inv;
}

// ---- K5: y[c] = mean_{b,p} x[b,c,p] * w[b,p] ----
__global__ void k_reduce_y(const float* __restrict__ x, const float* __restrict__ wsm,
                           float* __restrict__ y) {
    int c = blockIdx.x;
    int t = threadIdx.x;
    float acc = 0.f;
    for (int b = 0; b < 8; ++b) {
        const float* xb = x + ((size_t)(b * C_ + c)) * HW_;
        const float* wb = wsm + b * HW_;
#pragma unroll
        for (int i = 0; i < 4; ++i) {
            int p = t + i * 256;
            acc += xb[p] * wb[p];
        }
    }
#pragma unroll
    for (int off = 1; off < 64; off <<= 1) acc += __shfl_xor(acc, off);
    __shared__ float red[4];
    if ((t & 63) == 0) red[t >> 6] = acc;
    __syncthreads();
    if (t == 0) y[c] = (red[0] + red[1] + red[2] + red[3]) * (1.0f / 8192.0f);
}

// ---- K6: x_proto[d] = W6[d,:] . y + b6[d] ----
__global__ void k_proto(const float* __restrict__ W6, const float* __restrict__ b6,
                        const float* __restrict__ y, float* __restrict__ proto) {
    int d = blockIdx.x;
    int lane = threadIdx.x;
    float acc = 0.f;
#pragma unroll
    for (int i = 0; i < 8; ++i)
        acc += W6[(size_t)d * C_ + lane + i * 64] * y[lane + i * 64];
#pragma unroll
    for (int off = 1; off < 64; off <<= 1) acc += __shfl_xor(acc, off);
    if (lane == 0) proto[d] = acc + b6[d];
}

// ---- K7: out = x * proto[c] ----
__global__ void k_final(const float* __restrict__ x, const float* __restrict__ proto,
                        float* __restrict__ out) {
    int idx = blockIdx.x * 256 + threadIdx.x;
    float4 v = ((const float4*)x)[idx];
    int c = (idx >> 8) & 511;
    float p = proto[c];
    v.x *= p; v.y *= p; v.z *= p; v.w *= p;
    ((float4*)out)[idx] = v;
}

extern "C" void kernel_launch(void* const* d_in, const int* in_sizes, int n_in,
                              void* d_out, int out_size, void* d_ws, size_t ws_size,
                              hipStream_t stream) {
    const float* x  = (const float*)d_in[0];
    const float* Wq = (const float*)d_in[1];
    const float* bq = (const float*)d_in[2];
    const float* Wk = (const float*)d_in[3];
    const float* bk = (const float*)d_in[4];
    const float* W6 = (const float*)d_in[5];
    const float* b6 = (const float*)d_in[6];
    float* out = (float*)d_out;

    char* ws = (char*)d_ws;
    bf16_t* xT    = (bf16_t*)(ws);                 // 8.4 MB (dead after k_gemm_qk)
    float*  Mout  = (float*)(ws);                  // 8192*8*4 = 256 KB, aliases xT
    bf16_t* wqb   = (bf16_t*)(ws + 8388608);
    bf16_t* wkb   = (bf16_t*)(ws + 8912896);
    bf16_t* qb    = (bf16_t*)(ws + 9437184);
    bf16_t* kb    = (bf16_t*)(ws + 17825792);
    float*  wsm   = (float*)(ws + 26476544);
    float*  yv    = (float*)(ws + 26509312);
    float*  proto = (float*)(ws + 26511360);

    hipLaunchKernelGGL(k_cvt_w, dim3(1024), dim3(256), 0, stream, Wq, Wk, wqb, wkb);
    hipLaunchKernelGGL(k_transpose, dim3(16, 8, 8), dim3(256), 0, stream, x, xT);
    hipLaunchKernelGGL(k_gemm_qk, dim3(512), dim3(256), 0, stream,
                       xT, wqb, wkb, bq, bk, qb, kb);
    hipLaunchKernelGGL(k_gemm_max8, dim3(256), dim3(512), 0, stream, qb, kb, Mout);
    hipLaunchKernelGGL(k_softmax, dim3(8), dim3(256), 0, stream, Mout, wsm);
    hipLaunchKernelGGL(k_reduce_y, dim3(512), dim3(256), 0, stream, x, wsm, yv);
    hipLaunchKernelGGL(k_proto, dim3(512), dim3(64), 0, stream, W6, b6, yv, proto);
    hipLaunchKernelGGL(k_final, dim3(4096), dim3(256), 0, stream, x, proto, out);
}

// Round 5
// 103.948 us; speedup vs baseline: 1.3414x; 1.0325x over previous
//
#include <hip/hip_runtime.h>
#include <hip/hip_bf16.h>

typedef __bf16 bf16_t;
typedef __bf16 bf16x8 __attribute__((ext_vector_type(8)));
typedef float f32x4 __attribute__((ext_vector_type(4)));

#define B_   8
#define C_   512
#define HW_  1024
#define NPIX 8192

// ---- async global->LDS (16B per lane) ----
typedef __attribute__((address_space(3))) void lds_vp;
typedef const __attribute__((address_space(1))) void gbl_vp;
__device__ __forceinline__ void gload_lds16(const void* g, void* l) {
    __builtin_amdgcn_global_load_lds((gbl_vp*)g, (lds_vp*)l, 16, 0, 0);
}

// Stage a 128x64 bf16 tile (row-major, ld=ldk) into LDS [128][64] linearly.
__device__ __forceinline__ void stage128x64(const bf16_t* __restrict__ g, int ldk,
                                            bf16_t* lds, int tid) {
    int w64 = tid & ~63;
#pragma unroll
    for (int s = 0; s < 4; ++s) {
        int u = s * 256 + tid;
        const bf16_t* src = g + (size_t)(u >> 3) * ldk + (u & 7) * 8;
        gload_lds16((const void*)src, (void*)(lds + (size_t)(s * 256 + w64) * 8));
    }
}

// ---- K1a: convert weights to bf16 ----
__global__ void k_cvt_w(const float* __restrict__ Wq, const float* __restrict__ Wk,
                        bf16_t* __restrict__ wq, bf16_t* __restrict__ wk) {
    int i = blockIdx.x * 256 + threadIdx.x;
    wq[i] = (bf16_t)Wq[i];
    wk[i] = (bf16_t)Wk[i];
}

// ---- K1b: x [B,C,HW] f32 -> xT [B*HW, C] bf16 ----
__global__ void k_transpose(const float* __restrict__ x, bf16_t* __restrict__ xT) {
    __shared__ bf16_t tile[64 * 66];
    int p0 = blockIdx.x * 64, c0 = blockIdx.y * 64, b = blockIdx.z;
    int t = threadIdx.x;
#pragma unroll
    for (int s = 0; s < 16; ++s) {
        int u = s * 256 + t;
        int cr = u >> 6, pc = u & 63;
        tile[cr * 66 + pc] = (bf16_t)x[((size_t)(b * C_ + c0 + cr)) * HW_ + p0 + pc];
    }
    __syncthreads();
#pragma unroll
    for (int s = 0; s < 16; ++s) {
        int u = s * 256 + t;
        int pr = u >> 6, cc = u & 63;
        xT[((size_t)(b * HW_ + p0 + pr)) * C_ + c0 + cc] = tile[cc * 66 + pr];
    }
}

// ---- K2: q/k projection GEMM (m97 structure, 128x128 tiles) ----
__launch_bounds__(256, 2)
__global__ void k_gemm_qk(const bf16_t* __restrict__ xT,
                          const bf16_t* __restrict__ wq, const bf16_t* __restrict__ wk,
                          const float* __restrict__ bq, const float* __restrict__ bk,
                          bf16_t* __restrict__ qo, bf16_t* __restrict__ ko) {
    __shared__ bf16_t As[128 * 64];
    __shared__ bf16_t Bs[128 * 64];
    int bid = blockIdx.x;
    int mtile = bid >> 3;
    int nt = bid & 7;
    const bf16_t* wsel = (nt < 4) ? wq : wk;
    const float*  bsel = (nt < 4) ? bq : bk;
    bf16_t*       osel = (nt < 4) ? qo : ko;
    int nb = (nt & 3) * 128;
    int i0 = mtile * 128;
    int tid = threadIdx.x;
    int lane = tid & 63, w = tid >> 6;
    int wr = w >> 1, wc = w & 1, lr = lane & 15, lg = lane >> 4;

    f32x4 acc[4][4];
#pragma unroll
    for (int mi = 0; mi < 4; ++mi)
#pragma unroll
        for (int ni = 0; ni < 4; ++ni)
#pragma unroll
            for (int r = 0; r < 4; ++r) acc[mi][ni][r] = 0.f;

    for (int kt = 0; kt < 8; ++kt) {
        int k0 = kt * 64;
        stage128x64(xT + (size_t)i0 * 512 + k0, 512, As, tid);
        stage128x64(wsel + (size_t)nb * 512 + k0, 512, Bs, tid);
        __syncthreads();
#pragma unroll
        for (int kk = 0; kk < 2; ++kk) {
            bf16x8 af[4], bfr[4];
#pragma unroll
            for (int mi = 0; mi < 4; ++mi)
                af[mi] = *reinterpret_cast<const bf16x8*>(
                    &As[(wr * 64 + mi * 16 + lr) * 64 + kk * 32 + lg * 8]);
#pragma unroll
            for (int ni = 0; ni < 4; ++ni)
                bfr[ni] = *reinterpret_cast<const bf16x8*>(
                    &Bs[(wc * 64 + ni * 16 + lr) * 64 + kk * 32 + lg * 8]);
#pragma unroll
            for (int mi = 0; mi < 4; ++mi)
#pragma unroll
                for (int ni = 0; ni < 4; ++ni)
                    acc[mi][ni] = __builtin_amdgcn_mfma_f32_16x16x32_bf16(
                        af[mi], bfr[ni], acc[mi][ni], 0, 0, 0);
        }
        __syncthreads();
    }
#pragma unroll
    for (int ni = 0; ni < 4; ++ni) {
        int col = nb + wc * 64 + ni * 16 + lr;
        float bias = bsel[col];
#pragma unroll
        for (int mi = 0; mi < 4; ++mi) {
            int rowb = i0 + wr * 64 + mi * 16 + lg * 4;
#pragma unroll
            for (int r = 0; r < 4; ++r)
                osel[(size_t)(rowb + r) * 512 + col] = (bf16_t)(acc[mi][ni][r] + bias);
        }
    }
}

// ---- K3: score GEMM + per-key-image max ----
// 256 blocks = (q-panel 256 rows) x (key image). 32 K-tiles (4 n-chunks x 8).
// 8 LDS regions of [128 rows][128 B]: A_rh{0,1} x dbuf2 at 0..65535,
// B_rh{0,1} x dbuf2 at 65536..131071.
// Swizzle: byte-in-row ^= (row&7)<<4  (3 row bits into byte bits 4-6).
// Read slot = (kh*4+lg) ^ (lr&7): every 8-lane group covers all 8 slots
// exactly once -> dense, conflict-free.
// Stage ledger (iter i: ta=2i d0, tb=2i+1 d1, tc=2i+2, td=2i+3):
//   ph1:A0d1(tb) ph2:B1d1(tb) ph3:A1d1(tb) ph4:B0d0(tc)+vmcnt(2)
//   ph5:A0d0(tc) ph6:B1d0(tc) ph7:A1d0(tc) ph8:B0d1(td)+vmcnt(2)

#define STAGE_A(RH, D, T)                                                          \
    gload_lds16((const void*)(q + srcA + (size_t)((RH) * 128) * 512 +              \
                              ((T) & 7) * 64),                                     \
                (void*)(ldsb + (RH) * 32768 + (D) * 16384 + ldw));                 \
    gload_lds16((const void*)(q + srcA + (size_t)((RH) * 128 + 64) * 512 +         \
                              ((T) & 7) * 64),                                     \
                (void*)(ldsb + (RH) * 32768 + (D) * 16384 + 8192 + ldw));

#define STAGE_B(RH, D, T)                                                          \
    gload_lds16((const void*)(kb + srcB +                                          \
                              (size_t)(((T) >> 3) * 256 + (RH) * 128) * 512 +      \
                              ((T) & 7) * 64),                                     \
                (void*)(ldsb + 65536 + (RH) * 32768 + (D) * 16384 + ldw));         \
    gload_lds16((const void*)(kb + srcB +                                          \
                              (size_t)(((T) >> 3) * 256 + (RH) * 128 + 64) * 512 + \
                              ((T) & 7) * 64),                                     \
                (void*)(ldsb + 65536 + (RH) * 32768 + (D) * 16384 + 8192 + ldw));

#define PHASE(D, KH, MH, STAGE_STMT, VM_STMT)                                      \
    {                                                                              \
        const char* Ab = ldsb + wr * 32768 + (D) * 16384;                          \
        const char* Bb = ldsb + 65536 + (wc >> 1) * 32768 + (D) * 16384;           \
        _Pragma("unroll")                                                          \
        for (int mi = 0; mi < 4; ++mi)                                             \
            af[mi] = *(const bf16x8*)(Ab + (aswz ^ ((KH) * 64)) +                  \
                                      ((MH) * 4 + mi) * 2048);                     \
        if ((MH) == 0) {                                                           \
            _Pragma("unroll")                                                      \
            for (int ni = 0; ni < 4; ++ni)                                         \
                bf[ni] = *(const bf16x8*)(Bb + (bswz ^ ((KH) * 64)) + ni * 2048);  \
        }                                                                          \
        STAGE_STMT;                                                                \
        __builtin_amdgcn_s_barrier();                                              \
        asm volatile("s_waitcnt lgkmcnt(0)" ::: "memory");                         \
        __builtin_amdgcn_sched_barrier(0);                                         \
        __builtin_amdgcn_s_setprio(1);                                             \
        _Pragma("unroll")                                                          \
        for (int mi = 0; mi < 4; ++mi)                                             \
            _Pragma("unroll")                                                      \
            for (int ni = 0; ni < 4; ++ni)                                         \
                acc[(MH) * 4 + mi][ni] = __builtin_amdgcn_mfma_f32_16x16x32_bf16(  \
                    af[mi], bf[ni], acc[(MH) * 4 + mi][ni], 0, 0, 0);              \
        __builtin_amdgcn_s_setprio(0);                                             \
        VM_STMT;                                                                   \
        __builtin_amdgcn_s_barrier();                                              \
    }

__global__ __launch_bounds__(512, 2)
void k_gemm_max8(const bf16_t* __restrict__ q, const bf16_t* __restrict__ kp,
                 float* __restrict__ Mout) {
    __shared__ __align__(16) bf16_t lds[65536];   // 128 KiB
    char* ldsb = (char*)lds;
    int bid = blockIdx.x;           // 256 blocks
    int img = bid & 7;              // XCD-local key image
    int qp = bid >> 3;              // 0..31
    int i0 = qp * 256;
    const bf16_t* kb = kp + (size_t)img * HW_ * C_;
    int tid = threadIdx.x;
    int lane = tid & 63, w = tid >> 6;
    int wr = w >> 2, wc = w & 3;    // 2 x 4 wave grid
    int lr = lane & 15, lg = lane >> 4;
    // read offsets: slot = lg ^ (lr&7) (^ kh*4 via XOR of KH*64 in PHASE)
    int kswz = (lg ^ (lr & 7)) << 4;
    int aswz = lr * 128 + kswz;
    int bswz = ((wc & 1) * 64 + lr) * 128 + kswz;

    // staging: thread t covers LDS bytes [t*16, t*16+16) of each 8KB pass;
    // row = pass*64 + (t>>3), byte-in-row = (t&7)*16. Inverse-swizzled source:
    // k-elems = 8 * ((t&7) ^ ((t>>3)&7))
    int srow = tid >> 3;
    int sk = (((tid & 7) ^ ((tid >> 3) & 7))) << 3;
    size_t srcA = (size_t)(i0 + srow) * 512 + sk;
    size_t srcB = (size_t)srow * 512 + sk;
    int ldw = (tid >> 6) * 1024;    // wave-uniform LDS byte base

    f32x4 acc[8][4];
    bf16x8 af[4], bf[4];
    float rm[8][4];
#pragma unroll
    for (int mi = 0; mi < 8; ++mi)
#pragma unroll
        for (int ni = 0; ni < 4; ++ni)
#pragma unroll
            for (int r = 0; r < 4; ++r) acc[mi][ni][r] = 0.f;
#pragma unroll
    for (int mi = 0; mi < 8; ++mi)
#pragma unroll
        for (int r = 0; r < 4; ++r) rm[mi][r] = -3.4e38f;

    // prologue: t0 all 4 regions (d0), t1 B0 (d1)
    STAGE_B(0, 0, 0) STAGE_A(0, 0, 0) STAGE_B(1, 0, 0) STAGE_A(1, 0, 0)
    STAGE_B(0, 1, 1)
    asm volatile("s_waitcnt vmcnt(2)" ::: "memory");
    __builtin_amdgcn_s_barrier();

    for (int i = 0; i < 16; ++i) {
        int tb = 2 * i + 1, tc = 2 * i + 2, td = 2 * i + 3;
        bool s = (i < 15);
        // ph1: ta kh0 m0-3 ; stage A0d1(tb)
        PHASE(0, 0, 0, { STAGE_A(0, 1, tb) }, {})
        // ph2: ta kh0 m4-7 ; stage B1d1(tb)
        PHASE(0, 0, 1, { STAGE_B(1, 1, tb) }, {})
        // ph3: ta kh1 m0-3 ; stage A1d1(tb)
        PHASE(0, 1, 0, { STAGE_A(1, 1, tb) }, {})
        // ph4: ta kh1 m4-7 ; stage B0d0(tc) ; vmcnt forces tb landed
        PHASE(0, 1, 1, { if (s) { STAGE_B(0, 0, tc) } },
              { if (s) { asm volatile("s_waitcnt vmcnt(2)" ::: "memory"); }
                else   { asm volatile("s_waitcnt vmcnt(0)" ::: "memory"); } })
        // ph5: tb kh0 m0-3 ; stage A0d0(tc)
        PHASE(1, 0, 0, { if (s) { STAGE_A(0, 0, tc) } }, {})
        // ph6: tb kh0 m4-7 ; stage B1d0(tc)
        PHASE(1, 0, 1, { if (s) { STAGE_B(1, 0, tc) } }, {})
        // ph7: tb kh1 m0-3 ; stage A1d0(tc)
        PHASE(1, 1, 0, { if (s) { STAGE_A(1, 0, tc) } }, {})
        // ph8: tb kh1 m4-7 ; stage B0d1(td) ; vmcnt forces tc landed
        PHASE(1, 1, 1, { if (s) { STAGE_B(0, 1, td) } },
              { if (s) { asm volatile("s_waitcnt vmcnt(2)" ::: "memory"); } })
        if ((i & 3) == 3) {   // n-chunk complete: fold acc into rm, reset acc
#pragma unroll
            for (int mi = 0; mi < 8; ++mi)
#pragma unroll
                for (int r = 0; r < 4; ++r) {
                    float v = fmaxf(fmaxf(acc[mi][0][r], acc[mi][1][r]),
                                    fmaxf(acc[mi][2][r], acc[mi][3][r]));
                    rm[mi][r] = fmaxf(rm[mi][r], v);
#pragma unroll
                    for (int ni = 0; ni < 4; ++ni) acc[mi][ni][r] = 0.f;
                }
        }
    }

    // epilogue: reduce across 16 col-lanes, then across the 4 wc waves
#pragma unroll
    for (int mi = 0; mi < 8; ++mi)
#pragma unroll
        for (int r = 0; r < 4; ++r) {
            float v = rm[mi][r];
#pragma unroll
            for (int off = 1; off < 16; off <<= 1) v = fmaxf(v, __shfl_xor(v, off));
            rm[mi][r] = v;
        }
    float* sm = (float*)lds;
    if (lr == 0) {
#pragma unroll
        for (int mi = 0; mi < 8; ++mi)
#pragma unroll
            for (int r = 0; r < 4; ++r)
                sm[wc * 256 + wr * 128 + mi * 16 + lg * 4 + r] = rm[mi][r];
    }
    __syncthreads();
    if (tid < 256) {
        float v = fmaxf(fmaxf(sm[tid], sm[256 + tid]),
                        fmaxf(sm[512 + tid], sm[768 + tid]));
        Mout[(size_t)(i0 + tid) * 8 + img] = v;
    }
}

// ---- K4: mean over key images, scale, softmax per query image ----
__global__ void k_softmax(const float* __restrict__ Mout, float* __restrict__ wsm) {
    int b = blockIdx.x;
    int t = threadIdx.x;
    __shared__ float red[16];
    const float scale = 0.044194173824159216f;  // 1/sqrt(512)
    float s[4];
#pragma unroll
    for (int i = 0; i < 4; ++i) {
        int p = t + i * 256;
        const float* row = &Mout[(size_t)(b * 1024 + p) * 8];
        float acc = 0.f;
#pragma unroll
        for (int j = 0; j < 8; ++j) acc += row[j];
        s[i] = acc * (scale / 8.0f);
    }
    float m = fmaxf(fmaxf(s[0], s[1]), fmaxf(s[2], s[3]));
#pragma unroll
    for (int off = 1; off < 64; off <<= 1) m = fmaxf(m, __shfl_xor(m, off));
    if ((t & 63) == 0) red[t >> 6] = m;
    __syncthreads();
    float m4 = fmaxf(fmaxf(red[0], red[1]), fmaxf(red[2], red[3]));
    float e[4], sum = 0.f;
#pragma unroll
    for (int i = 0; i < 4; ++i) { e[i] = __expf(s[i] - m4); sum += e[i]; }
#pragma unroll
    for (int off = 1; off < 64; off <<= 1) sum += __shfl_xor(sum, off);
    if ((t & 63) == 0) red[8 + (t >> 6)] = sum;
    __syncthreads();
    float tot = red[8] + red[9] + red[10] + red[11];
    float inv = 1.0f / tot;
#pragma unroll
    for (int i = 0; i < 4; ++i) wsm[b * 1024 + t + i * 256] = e[i] * inv;
}

// ---- K5: y[c] = mean_{b,p} x[b,c,p] * w[b,p] ----
__global__ void k_reduce_y(const float* __restrict__ x, const float* __restrict__ wsm,
                           float* __restrict__ y) {
    int c = blockIdx.x;
    int t = threadIdx.x;
    float acc = 0.f;
    for (int b = 0; b < 8; ++b) {
        const float* xb = x + ((size_t)(b * C_ + c)) * HW_;
        const float* wb = wsm + b * HW_;
#pragma unroll
        for (int i = 0; i < 4; ++i) {
            int p = t + i * 256;
            acc += xb[p] * wb[p];
        }
    }
#pragma unroll
    for (int off = 1; off < 64; off <<= 1) acc += __shfl_xor(acc, off);
    __shared__ float red[4];
    if ((t & 63) == 0) red[t >> 6] = acc;
    __syncthreads();
    if (t == 0) y[c] = (red[0] + red[1] + red[2] + red[3]) * (1.0f / 8192.0f);
}

// ---- K6: x_proto[d] = W6[d,:] . y + b6[d] ----
__global__ void k_proto(const float* __restrict__ W6, const float* __restrict__ b6,
                        const float* __restrict__ y, float* __restrict__ proto) {
    int d = blockIdx.x;
    int lane = threadIdx.x;
    float acc = 0.f;
#pragma unroll
    for (int i = 0; i < 8; ++i)
        acc += W6[(size_t)d * C_ + lane + i * 64] * y[lane + i * 64];
#pragma unroll
    for (int off = 1; off < 64; off <<= 1) acc += __shfl_xor(acc, off);
    if (lane == 0) proto[d] = acc + b6[d];
}

// ---- K7: out = x * proto[c] ----
__global__ void k_final(const float* __restrict__ x, const float* __restrict__ proto,
                        float* __restrict__ out) {
    int idx = blockIdx.x * 256 + threadIdx.x;
    float4 v = ((const float4*)x)[idx];
    int c = (idx >> 8) & 511;
    float p = proto[c];
    v.x *= p; v.y *= p; v.z *= p; v.w *= p;
    ((float4*)out)[idx] = v;
}

extern "C" void kernel_launch(void* const* d_in, const int* in_sizes, int n_in,
                              void* d_out, int out_size, void* d_ws, size_t ws_size,
                              hipStream_t stream) {
    const float* x  = (const float*)d_in[0];
    const float* Wq = (const float*)d_in[1];
    const float* bq = (const float*)d_in[2];
    const float* Wk = (const float*)d_in[3];
    const float* bk = (const float*)d_in[4];
    const float* W6 = (const float*)d_in[5];
    const float* b6 = (const float*)d_in[6];
    float* out = (float*)d_out;

    char* ws = (char*)d_ws;
    bf16_t* xT    = (bf16_t*)(ws);                 // 8.4 MB (dead after k_gemm_qk)
    float*  Mout  = (float*)(ws);                  // 8192*8*4 = 256 KB, aliases xT
    bf16_t* wqb   = (bf16_t*)(ws + 8388608);
    bf16_t* wkb   = (bf16_t*)(ws + 8912896);
    bf16_t* qb    = (bf16_t*)(ws + 9437184);
    bf16_t* kb    = (bf16_t*)(ws + 17825792);
    float*  wsm   = (float*)(ws + 26476544);
    float*  yv    = (float*)(ws + 26509312);
    float*  proto = (float*)(ws + 26511360);

    hipLaunchKernelGGL(k_cvt_w, dim3(1024), dim3(256), 0, stream, Wq, Wk, wqb, wkb);
    hipLaunchKernelGGL(k_transpose, dim3(16, 8, 8), dim3(256), 0, stream, x, xT);
    hipLaunchKernelGGL(k_gemm_qk, dim3(512), dim3(256), 0, stream,
                       xT, wqb, wkb, bq, bk, qb, kb);
    hipLaunchKernelGGL(k_gemm_max8, dim3(256), dim3(512), 0, stream, qb, kb, Mout);
    hipLaunchKernelGGL(k_softmax, dim3(8), dim3(256), 0, stream, Mout, wsm);
    hipLaunchKernelGGL(k_reduce_y, dim3(512), dim3(256), 0, stream, x, wsm, yv);
    hipLaunchKernelGGL(k_proto, dim3(512), dim3(64), 0, stream, W6, b6, yv, proto);
    hipLaunchKernelGGL(k_final, dim3(4096), dim3(256), 0, stream, x, proto, out);
}

// Round 6
// 103.694 us; speedup vs baseline: 1.3447x; 1.0024x over previous
//
#include <hip/hip_runtime.h>
#include <hip/hip_bf16.h>

typedef __bf16 bf16_t;
typedef __bf16 bf16x8 __attribute__((ext_vector_type(8)));
typedef float f32x4 __attribute__((ext_vector_type(4)));

#define B_   8
#define C_   512
#define HW_  1024
#define NPIX 8192

// ---- async global->LDS (16B per lane) ----
typedef __attribute__((address_space(3))) void lds_vp;
typedef const __attribute__((address_space(1))) void gbl_vp;
__device__ __forceinline__ void gload_lds16(const void* g, void* l) {
    __builtin_amdgcn_global_load_lds((gbl_vp*)g, (lds_vp*)l, 16, 0, 0);
}

// Stage a 128x64 bf16 tile (row-major, ld=ldk) into LDS [128][64] linearly.
__device__ __forceinline__ void stage128x64(const bf16_t* __restrict__ g, int ldk,
                                            bf16_t* lds, int tid) {
    int w64 = tid & ~63;
#pragma unroll
    for (int s = 0; s < 4; ++s) {
        int u = s * 256 + tid;
        const bf16_t* src = g + (size_t)(u >> 3) * ldk + (u & 7) * 8;
        gload_lds16((const void*)src, (void*)(lds + (size_t)(s * 256 + w64) * 8));
    }
}

// ---- K1a: convert weights to bf16 ----
__global__ void k_cvt_w(const float* __restrict__ Wq, const float* __restrict__ Wk,
                        bf16_t* __restrict__ wq, bf16_t* __restrict__ wk) {
    int i = blockIdx.x * 256 + threadIdx.x;
    wq[i] = (bf16_t)Wq[i];
    wk[i] = (bf16_t)Wk[i];
}

// ---- K1b: x [B,C,HW] f32 -> xT [B*HW, C] bf16 ----
__global__ void k_transpose(const float* __restrict__ x, bf16_t* __restrict__ xT) {
    __shared__ bf16_t tile[64 * 66];
    int p0 = blockIdx.x * 64, c0 = blockIdx.y * 64, b = blockIdx.z;
    int t = threadIdx.x;
#pragma unroll
    for (int s = 0; s < 16; ++s) {
        int u = s * 256 + t;
        int cr = u >> 6, pc = u & 63;
        tile[cr * 66 + pc] = (bf16_t)x[((size_t)(b * C_ + c0 + cr)) * HW_ + p0 + pc];
    }
    __syncthreads();
#pragma unroll
    for (int s = 0; s < 16; ++s) {
        int u = s * 256 + t;
        int pr = u >> 6, cc = u & 63;
        xT[((size_t)(b * HW_ + p0 + pr)) * C_ + c0 + cc] = tile[cc * 66 + pr];
    }
}

// ---- K2: q/k projection GEMM (m97 structure, 128x128 tiles) ----
__launch_bounds__(256, 2)
__global__ void k_gemm_qk(const bf16_t* __restrict__ xT,
                          const bf16_t* __restrict__ wq, const bf16_t* __restrict__ wk,
                          const float* __restrict__ bq, const float* __restrict__ bk,
                          bf16_t* __restrict__ qo, bf16_t* __restrict__ ko) {
    __shared__ bf16_t As[128 * 64];
    __shared__ bf16_t Bs[128 * 64];
    int bid = blockIdx.x;
    int mtile = bid >> 3;
    int nt = bid & 7;
    const bf16_t* wsel = (nt < 4) ? wq : wk;
    const float*  bsel = (nt < 4) ? bq : bk;
    bf16_t*       osel = (nt < 4) ? qo : ko;
    int nb = (nt & 3) * 128;
    int i0 = mtile * 128;
    int tid = threadIdx.x;
    int lane = tid & 63, w = tid >> 6;
    int wr = w >> 1, wc = w & 1, lr = lane & 15, lg = lane >> 4;

    f32x4 acc[4][4];
#pragma unroll
    for (int mi = 0; mi < 4; ++mi)
#pragma unroll
        for (int ni = 0; ni < 4; ++ni)
#pragma unroll
            for (int r = 0; r < 4; ++r) acc[mi][ni][r] = 0.f;

    for (int kt = 0; kt < 8; ++kt) {
        int k0 = kt * 64;
        stage128x64(xT + (size_t)i0 * 512 + k0, 512, As, tid);
        stage128x64(wsel + (size_t)nb * 512 + k0, 512, Bs, tid);
        __syncthreads();
#pragma unroll
        for (int kk = 0; kk < 2; ++kk) {
            bf16x8 af[4], bfr[4];
#pragma unroll
            for (int mi = 0; mi < 4; ++mi)
                af[mi] = *reinterpret_cast<const bf16x8*>(
                    &As[(wr * 64 + mi * 16 + lr) * 64 + kk * 32 + lg * 8]);
#pragma unroll
            for (int ni = 0; ni < 4; ++ni)
                bfr[ni] = *reinterpret_cast<const bf16x8*>(
                    &Bs[(wc * 64 + ni * 16 + lr) * 64 + kk * 32 + lg * 8]);
#pragma unroll
            for (int mi = 0; mi < 4; ++mi)
#pragma unroll
                for (int ni = 0; ni < 4; ++ni)
                    acc[mi][ni] = __builtin_amdgcn_mfma_f32_16x16x32_bf16(
                        af[mi], bfr[ni], acc[mi][ni], 0, 0, 0);
        }
        __syncthreads();
    }
#pragma unroll
    for (int ni = 0; ni < 4; ++ni) {
        int col = nb + wc * 64 + ni * 16 + lr;
        float bias = bsel[col];
#pragma unroll
        for (int mi = 0; mi < 4; ++mi) {
            int rowb = i0 + wr * 64 + mi * 16 + lg * 4;
#pragma unroll
            for (int r = 0; r < 4; ++r)
                osel[(size_t)(rowb + r) * 512 + col] = (bf16_t)(acc[mi][ni][r] + bias);
        }
    }
}

// ---- K3: score GEMM + per-key-image max ----
// 256 blocks = (q-panel 256 rows) x (key image). 32 K-tiles (4 n-chunks x 8).
// 8 LDS regions of [128 rows][128 B]: A_rh{0,1} x dbuf2 at 0..65535,
// B_rh{0,1} x dbuf2 at 65536..131071.
// Swizzle: byte-in-row ^= (row&7)<<4. Read slot = (kh*4+lg) ^ (lr&7):
// dense, conflict-free (verified: SQ_LDS_BANK_CONFLICT == 0).
// Stage ledger (iter i: ta=2i d0, tb=2i+1 d1, tc=2i+2, td=2i+3):
//   ph1:A0d1(tb) ph2:B1d1(tb) ph3:A1d1(tb) ph4:B0d0(tc)+vmcnt(2)
//   ph5:A0d0(tc) ph6:B1d0(tc) ph7:A1d0(tc) ph8:B0d1(td)+vmcnt(2)
// WAR: reads of phase p complete before their consuming MFMAs (counted
// lgkmcnt by compiler), which precede bar2(p), which precedes the p+1
// re-stage of those regions. lgkmcnt(0) before bar2 is free insurance.

#define STAGE_A(RH, D, T)                                                          \
    gload_lds16((const void*)(q + srcA + (size_t)((RH) * 128) * 512 +              \
                              ((T) & 7) * 64),                                     \
                (void*)(ldsb + (RH) * 32768 + (D) * 16384 + ldw));                 \
    gload_lds16((const void*)(q + srcA + (size_t)((RH) * 128 + 64) * 512 +         \
                              ((T) & 7) * 64),                                     \
                (void*)(ldsb + (RH) * 32768 + (D) * 16384 + 8192 + ldw));

#define STAGE_B(RH, D, T)                                                          \
    gload_lds16((const void*)(kb + srcB +                                          \
                              (size_t)(((T) >> 3) * 256 + (RH) * 128) * 512 +      \
                              ((T) & 7) * 64),                                     \
                (void*)(ldsb + 65536 + (RH) * 32768 + (D) * 16384 + ldw));         \
    gload_lds16((const void*)(kb + srcB +                                          \
                              (size_t)(((T) >> 3) * 256 + (RH) * 128 + 64) * 512 + \
                              ((T) & 7) * 64),                                     \
                (void*)(ldsb + 65536 + (RH) * 32768 + (D) * 16384 + 8192 + ldw));

#define PHASE(D, KH, MH, STAGE_STMT, VM_STMT)                                      \
    {                                                                              \
        const char* Ab = ldsb + wr * 32768 + (D) * 16384;                          \
        const char* Bb = ldsb + 65536 + (wc >> 1) * 32768 + (D) * 16384;           \
        _Pragma("unroll")                                                          \
        for (int mi = 0; mi < 4; ++mi)                                             \
            af[mi] = *(const bf16x8*)(Ab + (aswz ^ ((KH) * 64)) +                  \
                                      ((MH) * 4 + mi) * 2048);                     \
        if ((MH) == 0) {                                                           \
            _Pragma("unroll")                                                      \
            for (int ni = 0; ni < 4; ++ni)                                         \
                bf[ni] = *(const bf16x8*)(Bb + (bswz ^ ((KH) * 64)) + ni * 2048);  \
        }                                                                          \
        STAGE_STMT;                                                                \
        __builtin_amdgcn_s_barrier();                                              \
        __builtin_amdgcn_s_setprio(1);                                             \
        _Pragma("unroll")                                                          \
        for (int mi = 0; mi < 4; ++mi)                                             \
            _Pragma("unroll")                                                      \
            for (int ni = 0; ni < 4; ++ni)                                         \
                acc[(MH) * 4 + mi][ni] = __builtin_amdgcn_mfma_f32_16x16x32_bf16(  \
                    af[mi], bf[ni], acc[(MH) * 4 + mi][ni], 0, 0, 0);              \
        __builtin_amdgcn_s_setprio(0);                                             \
        asm volatile("s_waitcnt lgkmcnt(0)" ::: "memory");                         \
        VM_STMT;                                                                   \
        __builtin_amdgcn_s_barrier();                                              \
    }

__global__ __launch_bounds__(512, 2)
void k_gemm_max8(const bf16_t* __restrict__ q, const bf16_t* __restrict__ kp,
                 float* __restrict__ Mout) {
    __shared__ __align__(16) bf16_t lds[65536];   // 128 KiB
    char* ldsb = (char*)lds;
    int bid = blockIdx.x;           // 256 blocks
    int img = bid & 7;              // XCD-local key image
    int qp = bid >> 3;              // 0..31
    int i0 = qp * 256;
    const bf16_t* kb = kp + (size_t)img * HW_ * C_;
    int tid = threadIdx.x;
    int lane = tid & 63, w = tid >> 6;
    int wr = w >> 2, wc = w & 3;    // 2 x 4 wave grid
    int lr = lane & 15, lg = lane >> 4;
    // read offsets: slot = lg ^ (lr&7) (^ kh*4 via XOR of KH*64 in PHASE)
    int kswz = (lg ^ (lr & 7)) << 4;
    int aswz = lr * 128 + kswz;
    int bswz = ((wc & 1) * 64 + lr) * 128 + kswz;

    // staging: thread t covers LDS bytes [t*16, t*16+16) of each 8KB pass;
    // row = pass*64 + (t>>3), byte-in-row = (t&7)*16. Inverse-swizzled source:
    // k-elems = 8 * ((t&7) ^ ((t>>3)&7))
    int srow = tid >> 3;
    int sk = (((tid & 7) ^ ((tid >> 3) & 7))) << 3;
    size_t srcA = (size_t)(i0 + srow) * 512 + sk;
    size_t srcB = (size_t)srow * 512 + sk;
    int ldw = (tid >> 6) * 1024;    // wave-uniform LDS byte base

    f32x4 acc[8][4];
    bf16x8 af[4], bf[4];
    float rm[8][4];
#pragma unroll
    for (int mi = 0; mi < 8; ++mi)
#pragma unroll
        for (int ni = 0; ni < 4; ++ni)
#pragma unroll
            for (int r = 0; r < 4; ++r) acc[mi][ni][r] = 0.f;
#pragma unroll
    for (int mi = 0; mi < 8; ++mi)
#pragma unroll
        for (int r = 0; r < 4; ++r) rm[mi][r] = -3.4e38f;

    // prologue: t0 all 4 regions (d0), t1 B0 (d1)
    STAGE_B(0, 0, 0) STAGE_A(0, 0, 0) STAGE_B(1, 0, 0) STAGE_A(1, 0, 0)
    STAGE_B(0, 1, 1)
    asm volatile("s_waitcnt vmcnt(2)" ::: "memory");
    __builtin_amdgcn_s_barrier();

    for (int i = 0; i < 16; ++i) {
        int tb = 2 * i + 1, tc = 2 * i + 2, td = 2 * i + 3;
        bool s = (i < 15);
        // ph1: ta kh0 m0-3 ; stage A0d1(tb)
        PHASE(0, 0, 0, { STAGE_A(0, 1, tb) }, {})
        // ph2: ta kh0 m4-7 ; stage B1d1(tb)
        PHASE(0, 0, 1, { STAGE_B(1, 1, tb) }, {})
        // ph3: ta kh1 m0-3 ; stage A1d1(tb)
        PHASE(0, 1, 0, { STAGE_A(1, 1, tb) }, {})
        // ph4: ta kh1 m4-7 ; stage B0d0(tc) ; vmcnt forces tb landed
        PHASE(0, 1, 1, { if (s) { STAGE_B(0, 0, tc) } },
              { if (s) { asm volatile("s_waitcnt vmcnt(2)" ::: "memory"); }
                else   { asm volatile("s_waitcnt vmcnt(0)" ::: "memory"); } })
        // ph5: tb kh0 m0-3 ; stage A0d0(tc)
        PHASE(1, 0, 0, { if (s) { STAGE_A(0, 0, tc) } }, {})
        // ph6: tb kh0 m4-7 ; stage B1d0(tc)
        PHASE(1, 0, 1, { if (s) { STAGE_B(1, 0, tc) } }, {})
        // ph7: tb kh1 m0-3 ; stage A1d0(tc)
        PHASE(1, 1, 0, { if (s) { STAGE_A(1, 0, tc) } }, {})
        // ph8: tb kh1 m4-7 ; stage B0d1(td) ; vmcnt forces tc landed
        PHASE(1, 1, 1, { if (s) { STAGE_B(0, 1, td) } },
              { if (s) { asm volatile("s_waitcnt vmcnt(2)" ::: "memory"); } })
        if ((i & 3) == 3) {   // n-chunk complete: fold acc into rm, reset acc
#pragma unroll
            for (int mi = 0; mi < 8; ++mi)
#pragma unroll
                for (int r = 0; r < 4; ++r) {
                    float v = fmaxf(fmaxf(acc[mi][0][r], acc[mi][1][r]),
                                    fmaxf(acc[mi][2][r], acc[mi][3][r]));
                    rm[mi][r] = fmaxf(rm[mi][r], v);
#pragma unroll
                    for (int ni = 0; ni < 4; ++ni) acc[mi][ni][r] = 0.f;
                }
        }
    }

    // epilogue: reduce across 16 col-lanes, then across the 4 wc waves
#pragma unroll
    for (int mi = 0; mi < 8; ++mi)
#pragma unroll
        for (int r = 0; r < 4; ++r) {
            float v = rm[mi][r];
#pragma unroll
            for (int off = 1; off < 16; off <<= 1) v = fmaxf(v, __shfl_xor(v, off));
            rm[mi][r] = v;
        }
    float* sm = (float*)lds;
    if (lr == 0) {
#pragma unroll
        for (int mi = 0; mi < 8; ++mi)
#pragma unroll
            for (int r = 0; r < 4; ++r)
                sm[wc * 256 + wr * 128 + mi * 16 + lg * 4 + r] = rm[mi][r];
    }
    __syncthreads();
    if (tid < 256) {
        float v = fmaxf(fmaxf(sm[tid], sm[256 + tid]),
                        fmaxf(sm[512 + tid], sm[768 + tid]));
        Mout[(size_t)(i0 + tid) * 8 + img] = v;
    }
}

// ---- K4: mean over key images, scale, softmax per query image ----
__global__ void k_softmax(const float* __restrict__ Mout, float* __restrict__ wsm) {
    int b = blockIdx.x;
    int t = threadIdx.x;
    __shared__ float red[16];
    const float scale = 0.044194173824159216f;  // 1/sqrt(512)
    float s[4];
#pragma unroll
    for (int i = 0; i < 4; ++i) {
        int p = t + i * 256;
        const float* row = &Mout[(size_t)(b * 1024 + p) * 8];
        float acc = 0.f;
#pragma unroll
        for (int j = 0; j < 8; ++j) acc += row[j];
        s[i] = acc * (scale / 8.0f);
    }
    float m = fmaxf(fmaxf(s[0], s[1]), fmaxf(s[2], s[3]));
#pragma unroll
    for (int off = 1; off < 64; off <<= 1) m = fmaxf(m, __shfl_xor(m, off));
    if ((t & 63) == 0) red[t >> 6] = m;
    __syncthreads();
    float m4 = fmaxf(fmaxf(red[0], red[1]), fmaxf(red[2], red[3]));
    float e[4], sum = 0.f;
#pragma unroll
    for (int i = 0; i < 4; ++i) { e[i] = __expf(s[i] - m4); sum += e[i]; }
#pragma unroll
    for (int off = 1; off < 64; off <<= 1) sum += __shfl_xor(sum, off);
    if ((t & 63) == 0) red[8 + (t >> 6)] = sum;
    __syncthreads();
    float tot = red[8] + red[9] + red[10] + red[11];
    float inv = 1.0f / tot;
#pragma unroll
    for (int i = 0; i < 4; ++i) wsm[b * 1024 + t + i * 256] = e[i] * inv;
}

// ---- K5: y[c] = mean_{b,p} x[b,c,p] * w[b,p] ----
__global__ void k_reduce_y(const float* __restrict__ x, const float* __restrict__ wsm,
                           float* __restrict__ y) {
    int c = blockIdx.x;
    int t = threadIdx.x;
    float acc = 0.f;
    for (int b = 0; b < 8; ++b) {
        const float* xb = x + ((size_t)(b * C_ + c)) * HW_;
        const float* wb = wsm + b * HW_;
#pragma unroll
        for (int i = 0; i < 4; ++i) {
            int p = t + i * 256;
            acc += xb[p] * wb[p];
        }
    }
#pragma unroll
    for (int off = 1; off < 64; off <<= 1) acc += __shfl_xor(acc, off);
    __shared__ float red[4];
    if ((t & 63) == 0) red[t >> 6] = acc;
    __syncthreads();
    if (t == 0) y[c] = (red[0] + red[1] + red[2] + red[3]) * (1.0f / 8192.0f);
}

// ---- K6: x_proto[d] = W6[d,:] . y + b6[d] ----
__global__ void k_proto(const float* __restrict__ W6, const float* __restrict__ b6,
                        const float* __restrict__ y, float* __restrict__ proto) {
    int d = blockIdx.x;
    int lane = threadIdx.x;
    float acc = 0.f;
#pragma unroll
    for (int i = 0; i < 8; ++i)
        acc += W6[(size_t)d * C_ + lane + i * 64] * y[lane + i * 64];
#pragma unroll
    for (int off = 1; off < 64; off <<= 1) acc += __shfl_xor(acc, off);
    if (lane == 0) proto[d] = acc + b6[d];
}

// ---- K7: out = x * proto[c] ----
__global__ void k_final(const float* __restrict__ x, const float* __restrict__ proto,
                        float* __restrict__ out) {
    int idx = blockIdx.x * 256 + threadIdx.x;
    float4 v = ((const float4*)x)[idx];
    int c = (idx >> 8) & 511;
    float p = proto[c];
    v.x *= p; v.y *= p; v.z *= p; v.w *= p;
    ((float4*)out)[idx] = v;
}

extern "C" void kernel_launch(void* const* d_in, const int* in_sizes, int n_in,
                              void* d_out, int out_size, void* d_ws, size_t ws_size,
                              hipStream_t stream) {
    const float* x  = (const float*)d_in[0];
    const float* Wq = (const float*)d_in[1];
    const float* bq = (const float*)d_in[2];
    const float* Wk = (const float*)d_in[3];
    const float* bk = (const float*)d_in[4];
    const float* W6 = (const float*)d_in[5];
    const float* b6 = (const float*)d_in[6];
    float* out = (float*)d_out;

    char* ws = (char*)d_ws;
    bf16_t* xT    = (bf16_t*)(ws);                 // 8.4 MB (dead after k_gemm_qk)
    float*  Mout  = (float*)(ws);                  // 8192*8*4 = 256 KB, aliases xT
    bf16_t* wqb   = (bf16_t*)(ws + 8388608);
    bf16_t* wkb   = (bf16_t*)(ws + 8912896);
    bf16_t* qb    = (bf16_t*)(ws + 9437184);
    bf16_t* kb    = (bf16_t*)(ws + 17825792);
    float*  wsm   = (float*)(ws + 26476544);
    float*  yv    = (float*)(ws + 26509312);
    float*  proto = (float*)(ws + 26511360);

    hipLaunchKernelGGL(k_cvt_w, dim3(1024), dim3(256), 0, stream, Wq, Wk, wqb, wkb);
    hipLaunchKernelGGL(k_transpose, dim3(16, 8, 8), dim3(256), 0, stream, x, xT);
    hipLaunchKernelGGL(k_gemm_qk, dim3(512), dim3(256), 0, stream,
                       xT, wqb, wkb, bq, bk, qb, kb);
    hipLaunchKernelGGL(k_gemm_max8, dim3(256), dim3(512), 0, stream, qb, kb, Mout);
    hipLaunchKernelGGL(k_softmax, dim3(8), dim3(256), 0, stream, Mout, wsm);
    hipLaunchKernelGGL(k_reduce_y, dim3(512), dim3(256), 0, stream, x, wsm, yv);
    hipLaunchKernelGGL(k_proto, dim3(512), dim3(64), 0, stream, W6, b6, yv, proto);
    hipLaunchKernelGGL(k_final, dim3(4096), dim3(256), 0, stream, x, proto, out);
}

// Round 7
// 103.170 us; speedup vs baseline: 1.3515x; 1.0051x over previous
//
#include <hip/hip_runtime.h>
#include <hip/hip_bf16.h>

typedef __bf16 bf16_t;
typedef __bf16 bf16x8 __attribute__((ext_vector_type(8)));
typedef float f32x4 __attribute__((ext_vector_type(4)));

#define B_   8
#define C_   512
#define HW_  1024
#define NPIX 8192

// ---- async global->LDS (16B per lane) ----
typedef __attribute__((address_space(3))) void lds_vp;
typedef const __attribute__((address_space(1))) void gbl_vp;
__device__ __forceinline__ void gload_lds16(const void* g, void* l) {
    __builtin_amdgcn_global_load_lds((gbl_vp*)g, (lds_vp*)l, 16, 0, 0);
}

// Stage a 128x64 bf16 tile (row-major, ld=ldk) into LDS [128][64] linearly.
__device__ __forceinline__ void stage128x64(const bf16_t* __restrict__ g, int ldk,
                                            bf16_t* lds, int tid) {
    int w64 = tid & ~63;
#pragma unroll
    for (int s = 0; s < 4; ++s) {
        int u = s * 256 + tid;
        const bf16_t* src = g + (size_t)(u >> 3) * ldk + (u & 7) * 8;
        gload_lds16((const void*)src, (void*)(lds + (size_t)(s * 256 + w64) * 8));
    }
}

// ---- K1a: convert weights to bf16 ----
__global__ void k_cvt_w(const float* __restrict__ Wq, const float* __restrict__ Wk,
                        bf16_t* __restrict__ wq, bf16_t* __restrict__ wk) {
    int i = blockIdx.x * 256 + threadIdx.x;
    wq[i] = (bf16_t)Wq[i];
    wk[i] = (bf16_t)Wk[i];
}

// ---- K1b: x [B,C,HW] f32 -> xT [B*HW, C] bf16 ----
__global__ void k_transpose(const float* __restrict__ x, bf16_t* __restrict__ xT) {
    __shared__ bf16_t tile[64 * 66];
    int p0 = blockIdx.x * 64, c0 = blockIdx.y * 64, b = blockIdx.z;
    int t = threadIdx.x;
#pragma unroll
    for (int s = 0; s < 16; ++s) {
        int u = s * 256 + t;
        int cr = u >> 6, pc = u & 63;
        tile[cr * 66 + pc] = (bf16_t)x[((size_t)(b * C_ + c0 + cr)) * HW_ + p0 + pc];
    }
    __syncthreads();
#pragma unroll
    for (int s = 0; s < 16; ++s) {
        int u = s * 256 + t;
        int pr = u >> 6, cc = u & 63;
        xT[((size_t)(b * HW_ + p0 + pr)) * C_ + c0 + cc] = tile[cc * 66 + pr];
    }
}

// ---- K2: q/k projection GEMM (m97 structure, 128x128 tiles) ----
__launch_bounds__(256, 2)
__global__ void k_gemm_qk(const bf16_t* __restrict__ xT,
                          const bf16_t* __restrict__ wq, const bf16_t* __restrict__ wk,
                          const float* __restrict__ bq, const float* __restrict__ bk,
                          bf16_t* __restrict__ qo, bf16_t* __restrict__ ko) {
    __shared__ bf16_t As[128 * 64];
    __shared__ bf16_t Bs[128 * 64];
    int bid = blockIdx.x;
    int mtile = bid >> 3;
    int nt = bid & 7;
    const bf16_t* wsel = (nt < 4) ? wq : wk;
    const float*  bsel = (nt < 4) ? bq : bk;
    bf16_t*       osel = (nt < 4) ? qo : ko;
    int nb = (nt & 3) * 128;
    int i0 = mtile * 128;
    int tid = threadIdx.x;
    int lane = tid & 63, w = tid >> 6;
    int wr = w >> 1, wc = w & 1, lr = lane & 15, lg = lane >> 4;

    f32x4 acc[4][4];
#pragma unroll
    for (int mi = 0; mi < 4; ++mi)
#pragma unroll
        for (int ni = 0; ni < 4; ++ni)
#pragma unroll
            for (int r = 0; r < 4; ++r) acc[mi][ni][r] = 0.f;

    for (int kt = 0; kt < 8; ++kt) {
        int k0 = kt * 64;
        stage128x64(xT + (size_t)i0 * 512 + k0, 512, As, tid);
        stage128x64(wsel + (size_t)nb * 512 + k0, 512, Bs, tid);
        __syncthreads();
#pragma unroll
        for (int kk = 0; kk < 2; ++kk) {
            bf16x8 af[4], bfr[4];
#pragma unroll
            for (int mi = 0; mi < 4; ++mi)
                af[mi] = *reinterpret_cast<const bf16x8*>(
                    &As[(wr * 64 + mi * 16 + lr) * 64 + kk * 32 + lg * 8]);
#pragma unroll
            for (int ni = 0; ni < 4; ++ni)
                bfr[ni] = *reinterpret_cast<const bf16x8*>(
                    &Bs[(wc * 64 + ni * 16 + lr) * 64 + kk * 32 + lg * 8]);
#pragma unroll
            for (int mi = 0; mi < 4; ++mi)
#pragma unroll
                for (int ni = 0; ni < 4; ++ni)
                    acc[mi][ni] = __builtin_amdgcn_mfma_f32_16x16x32_bf16(
                        af[mi], bfr[ni], acc[mi][ni], 0, 0, 0);
        }
        __syncthreads();
    }
#pragma unroll
    for (int ni = 0; ni < 4; ++ni) {
        int col = nb + wc * 64 + ni * 16 + lr;
        float bias = bsel[col];
#pragma unroll
        for (int mi = 0; mi < 4; ++mi) {
            int rowb = i0 + wr * 64 + mi * 16 + lg * 4;
#pragma unroll
            for (int r = 0; r < 4; ++r)
                osel[(size_t)(rowb + r) * 512 + col] = (bf16_t)(acc[mi][ni][r] + bias);
        }
    }
}

// ---- K3: score GEMM + per-key-image max ----
// 256 blocks = (q-panel 256 rows) x (key image). 32 K-tiles (4 n-chunks x 8).
// 8 LDS regions of [128 rows][128 B]: A_rh{0,1} x dbuf2 at 0..65535,
// B_rh{0,1} x dbuf2 at 65536..131071.
// Swizzle: byte-in-row ^= (row&7)<<4. Read slot = (kh*4+lg) ^ (lr&7):
// dense, conflict-free (verified: SQ_LDS_BANK_CONFLICT == 0).
// Stage ledger (iter i: ta=2i d0, tb=2i+1 d1, tc=2i+2, td=2i+3):
//   ph1:A0d1(tb) ph2:B1d1(tb) ph3:A1d1(tb) ph4:B0d0(tc)+vmcnt(2)
//   ph5:A0d0(tc) ph6:B1d0(tc) ph7:A1d0(tc) ph8:B0d1(td)+vmcnt(2)
// SINGLE barrier per phase: {reads; stage; MFMA; [vmcnt]; barrier}.
// WAR: each region staged exactly one phase after its last read; a wave's
// reads(p) are serviced before its MFMA(p) issues (HW interlock on the reg
// dep), MFMA precedes barrier(p), stage(p+1) issues after barrier(p).
// RAW: per-wave vmcnt BEFORE the barrier => barrier release certifies all
// waves' staged slices landed; each region is vmcnt-gated >=1 phase before
// its first read (ph8's own stage is covered by the next ph4 count).

#define STAGE_A(RH, D, T)                                                          \
    gload_lds16((const void*)(q + srcA + (size_t)((RH) * 128) * 512 +              \
                              ((T) & 7) * 64),                                     \
                (void*)(ldsb + (RH) * 32768 + (D) * 16384 + ldw));                 \
    gload_lds16((const void*)(q + srcA + (size_t)((RH) * 128 + 64) * 512 +         \
                              ((T) & 7) * 64),                                     \
                (void*)(ldsb + (RH) * 32768 + (D) * 16384 + 8192 + ldw));

#define STAGE_B(RH, D, T)                                                          \
    gload_lds16((const void*)(kb + srcB +                                          \
                              (size_t)(((T) >> 3) * 256 + (RH) * 128) * 512 +      \
                              ((T) & 7) * 64),                                     \
                (void*)(ldsb + 65536 + (RH) * 32768 + (D) * 16384 + ldw));         \
    gload_lds16((const void*)(kb + srcB +                                          \
                              (size_t)(((T) >> 3) * 256 + (RH) * 128 + 64) * 512 + \
                              ((T) & 7) * 64),                                     \
                (void*)(ldsb + 65536 + (RH) * 32768 + (D) * 16384 + 8192 + ldw));

#define PHASE(D, KH, MH, STAGE_STMT, VM_STMT)                                      \
    {                                                                              \
        const char* Ab = ldsb + wr * 32768 + (D) * 16384;                          \
        const char* Bb = ldsb + 65536 + (wc >> 1) * 32768 + (D) * 16384;           \
        _Pragma("unroll")                                                          \
        for (int mi = 0; mi < 4; ++mi)                                             \
            af[mi] = *(const bf16x8*)(Ab + (aswz ^ ((KH) * 64)) +                  \
                                      ((MH) * 4 + mi) * 2048);                     \
        if ((MH) == 0) {                                                           \
            _Pragma("unroll")                                                      \
            for (int ni = 0; ni < 4; ++ni)                                         \
                bf[ni] = *(const bf16x8*)(Bb + (bswz ^ ((KH) * 64)) + ni * 2048);  \
        }                                                                          \
        STAGE_STMT;                                                                \
        __builtin_amdgcn_s_setprio(1);                                             \
        _Pragma("unroll")                                                          \
        for (int mi = 0; mi < 4; ++mi)                                             \
            _Pragma("unroll")                                                      \
            for (int ni = 0; ni < 4; ++ni)                                         \
                acc[(MH) * 4 + mi][ni] = __builtin_amdgcn_mfma_f32_16x16x32_bf16(  \
                    af[mi], bf[ni], acc[(MH) * 4 + mi][ni], 0, 0, 0);              \
        __builtin_amdgcn_s_setprio(0);                                             \
        VM_STMT;                                                                   \
        __builtin_amdgcn_s_barrier();                                              \
    }

__global__ __launch_bounds__(512, 2)
void k_gemm_max8(const bf16_t* __restrict__ q, const bf16_t* __restrict__ kp,
                 float* __restrict__ Mout) {
    __shared__ __align__(16) bf16_t lds[65536];   // 128 KiB
    char* ldsb = (char*)lds;
    int bid = blockIdx.x;           // 256 blocks
    int img = bid & 7;              // XCD-local key image
    int qp = bid >> 3;              // 0..31
    int i0 = qp * 256;
    const bf16_t* kb = kp + (size_t)img * HW_ * C_;
    int tid = threadIdx.x;
    int lane = tid & 63, w = tid >> 6;
    int wr = w >> 2, wc = w & 3;    // 2 x 4 wave grid
    int lr = lane & 15, lg = lane >> 4;
    // read offsets: slot = lg ^ (lr&7) (^ kh*4 via XOR of KH*64 in PHASE)
    int kswz = (lg ^ (lr & 7)) << 4;
    int aswz = lr * 128 + kswz;
    int bswz = ((wc & 1) * 64 + lr) * 128 + kswz;

    // staging: thread t covers LDS bytes [t*16, t*16+16) of each 8KB pass;
    // row = pass*64 + (t>>3), byte-in-row = (t&7)*16. Inverse-swizzled source:
    // k-elems = 8 * ((t&7) ^ ((t>>3)&7))
    int srow = tid >> 3;
    int sk = (((tid & 7) ^ ((tid >> 3) & 7))) << 3;
    size_t srcA = (size_t)(i0 + srow) * 512 + sk;
    size_t srcB = (size_t)srow * 512 + sk;
    int ldw = (tid >> 6) * 1024;    // wave-uniform LDS byte base

    f32x4 acc[8][4];
    bf16x8 af[4], bf[4];
    float rm[8][4];
#pragma unroll
    for (int mi = 0; mi < 8; ++mi)
#pragma unroll
        for (int ni = 0; ni < 4; ++ni)
#pragma unroll
            for (int r = 0; r < 4; ++r) acc[mi][ni][r] = 0.f;
#pragma unroll
    for (int mi = 0; mi < 8; ++mi)
#pragma unroll
        for (int r = 0; r < 4; ++r) rm[mi][r] = -3.4e38f;

    // prologue: t0 all 4 regions (d0), t1 B0 (d1)
    STAGE_B(0, 0, 0) STAGE_A(0, 0, 0) STAGE_B(1, 0, 0) STAGE_A(1, 0, 0)
    STAGE_B(0, 1, 1)
    asm volatile("s_waitcnt vmcnt(2)" ::: "memory");
    __builtin_amdgcn_s_barrier();

    for (int i = 0; i < 16; ++i) {
        int tb = 2 * i + 1, tc = 2 * i + 2, td = 2 * i + 3;
        bool s = (i < 15);
        // ph1: ta kh0 m0-3 ; stage A0d1(tb)
        PHASE(0, 0, 0, { STAGE_A(0, 1, tb) }, {})
        // ph2: ta kh0 m4-7 ; stage B1d1(tb)
        PHASE(0, 0, 1, { STAGE_B(1, 1, tb) }, {})
        // ph3: ta kh1 m0-3 ; stage A1d1(tb)
        PHASE(0, 1, 0, { STAGE_A(1, 1, tb) }, {})
        // ph4: ta kh1 m4-7 ; stage B0d0(tc) ; vmcnt forces tb landed
        PHASE(0, 1, 1, { if (s) { STAGE_B(0, 0, tc) } },
              { if (s) { asm volatile("s_waitcnt vmcnt(2)" ::: "memory"); }
                else   { asm volatile("s_waitcnt vmcnt(0)" ::: "memory"); } })
        // ph5: tb kh0 m0-3 ; stage A0d0(tc)
        PHASE(1, 0, 0, { if (s) { STAGE_A(0, 0, tc) } }, {})
        // ph6: tb kh0 m4-7 ; stage B1d0(tc)
        PHASE(1, 0, 1, { if (s) { STAGE_B(1, 0, tc) } }, {})
        // ph7: tb kh1 m0-3 ; stage A1d0(tc)
        PHASE(1, 1, 0, { if (s) { STAGE_A(1, 0, tc) } }, {})
        // ph8: tb kh1 m4-7 ; stage B0d1(td) ; vmcnt forces tc landed
        PHASE(1, 1, 1, { if (s) { STAGE_B(0, 1, td) } },
              { if (s) { asm volatile("s_waitcnt vmcnt(2)" ::: "memory"); } })
        if ((i & 3) == 3) {   // n-chunk complete: fold acc into rm, reset acc
#pragma unroll
            for (int mi = 0; mi < 8; ++mi)
#pragma unroll
                for (int r = 0; r < 4; ++r) {
                    float v = fmaxf(fmaxf(acc[mi][0][r], acc[mi][1][r]),
                                    fmaxf(acc[mi][2][r], acc[mi][3][r]));
                    rm[mi][r] = fmaxf(rm[mi][r], v);
#pragma unroll
                    for (int ni = 0; ni < 4; ++ni) acc[mi][ni][r] = 0.f;
                }
        }
    }

    // epilogue: reduce across 16 col-lanes, then across the 4 wc waves
#pragma unroll
    for (int mi = 0; mi < 8; ++mi)
#pragma unroll
        for (int r = 0; r < 4; ++r) {
            float v = rm[mi][r];
#pragma unroll
            for (int off = 1; off < 16; off <<= 1) v = fmaxf(v, __shfl_xor(v, off));
            rm[mi][r] = v;
        }
    float* sm = (float*)lds;
    if (lr == 0) {
#pragma unroll
        for (int mi = 0; mi < 8; ++mi)
#pragma unroll
            for (int r = 0; r < 4; ++r)
                sm[wc * 256 + wr * 128 + mi * 16 + lg * 4 + r] = rm[mi][r];
    }
    __syncthreads();
    if (tid < 256) {
        float v = fmaxf(fmaxf(sm[tid], sm[256 + tid]),
                        fmaxf(sm[512 + tid], sm[768 + tid]));
        Mout[(size_t)(i0 + tid) * 8 + img] = v;
    }
}

// ---- K4: mean over key images, scale, softmax per query image ----
__global__ void k_softmax(const float* __restrict__ Mout, float* __restrict__ wsm) {
    int b = blockIdx.x;
    int t = threadIdx.x;
    __shared__ float red[16];
    const float scale = 0.044194173824159216f;  // 1/sqrt(512)
    float s[4];
#pragma unroll
    for (int i = 0; i < 4; ++i) {
        int p = t + i * 256;
        const float* row = &Mout[(size_t)(b * 1024 + p) * 8];
        float acc = 0.f;
#pragma unroll
        for (int j = 0; j < 8; ++j) acc += row[j];
        s[i] = acc * (scale / 8.0f);
    }
    float m = fmaxf(fmaxf(s[0], s[1]), fmaxf(s[2], s[3]));
#pragma unroll
    for (int off = 1; off < 64; off <<= 1) m = fmaxf(m, __shfl_xor(m, off));
    if ((t & 63) == 0) red[t >> 6] = m;
    __syncthreads();
    float m4 = fmaxf(fmaxf(red[0], red[1]), fmaxf(red[2], red[3]));
    float e[4], sum = 0.f;
#pragma unroll
    for (int i = 0; i < 4; ++i) { e[i] = __expf(s[i] - m4); sum += e[i]; }
#pragma unroll
    for (int off = 1; off < 64; off <<= 1) sum += __shfl_xor(sum, off);
    if ((t & 63) == 0) red[8 + (t >> 6)] = sum;
    __syncthreads();
    float tot = red[8] + red[9] + red[10] + red[11];
    float inv = 1.0f / tot;
#pragma unroll
    for (int i = 0; i < 4; ++i) wsm[b * 1024 + t + i * 256] = e[i] * inv;
}

// ---- K5: y[c] = mean_{b,p} x[b,c,p] * w[b,p] ----
__global__ void k_reduce_y(const float* __restrict__ x, const float* __restrict__ wsm,
                           float* __restrict__ y) {
    int c = blockIdx.x;
    int t = threadIdx.x;
    float acc = 0.f;
    for (int b = 0; b < 8; ++b) {
        const float* xb = x + ((size_t)(b * C_ + c)) * HW_;
        const float* wb = wsm + b * HW_;
#pragma unroll
        for (int i = 0; i < 4; ++i) {
            int p = t + i * 256;
            acc += xb[p] * wb[p];
        }
    }
#pragma unroll
    for (int off = 1; off < 64; off <<= 1) acc += __shfl_xor(acc, off);
    __shared__ float red[4];
    if ((t & 63) == 0) red[t >> 6] = acc;
    __syncthreads();
    if (t == 0) y[c] = (red[0] + red[1] + red[2] + red[3]) * (1.0f / 8192.0f);
}

// ---- K6: x_proto[d] = W6[d,:] . y + b6[d] ----
__global__ void k_proto(const float* __restrict__ W6, const float* __restrict__ b6,
                        const float* __restrict__ y, float* __restrict__ proto) {
    int d = blockIdx.x;
    int lane = threadIdx.x;
    float acc = 0.f;
#pragma unroll
    for (int i = 0; i < 8; ++i)
        acc += W6[(size_t)d * C_ + lane + i * 64] * y[lane + i * 64];
#pragma unroll
    for (int off = 1; off < 64; off <<= 1) acc += __shfl_xor(acc, off);
    if (lane == 0) proto[d] = acc + b6[d];
}

// ---- K7: out = x * proto[c] ----
__global__ void k_final(const float* __restrict__ x, const float* __restrict__ proto,
                        float* __restrict__ out) {
    int idx = blockIdx.x * 256 + threadIdx.x;
    float4 v = ((const float4*)x)[idx];
    int c = (idx >> 8) & 511;
    float p = proto[c];
    v.x *= p; v.y *= p; v.z *= p; v.w *= p;
    ((float4*)out)[idx] = v;
}

extern "C" void kernel_launch(void* const* d_in, const int* in_sizes, int n_in,
                              void* d_out, int out_size, void* d_ws, size_t ws_size,
                              hipStream_t stream) {
    const float* x  = (const float*)d_in[0];
    const float* Wq = (const float*)d_in[1];
    const float* bq = (const float*)d_in[2];
    const float* Wk = (const float*)d_in[3];
    const float* bk = (const float*)d_in[4];
    const float* W6 = (const float*)d_in[5];
    const float* b6 = (const float*)d_in[6];
    float* out = (float*)d_out;

    char* ws = (char*)d_ws;
    bf16_t* xT    = (bf16_t*)(ws);                 // 8.4 MB (dead after k_gemm_qk)
    float*  Mout  = (float*)(ws);                  // 8192*8*4 = 256 KB, aliases xT
    bf16_t* wqb   = (bf16_t*)(ws + 8388608);
    bf16_t* wkb   = (bf16_t*)(ws + 8912896);
    bf16_t* qb    = (bf16_t*)(ws + 9437184);
    bf16_t* kb    = (bf16_t*)(ws + 17825792);
    float*  wsm   = (float*)(ws + 26476544);
    float*  yv    = (float*)(ws + 26509312);
    float*  proto = (float*)(ws + 26511360);

    hipLaunchKernelGGL(k_cvt_w, dim3(1024), dim3(256), 0, stream, Wq, Wk, wqb, wkb);
    hipLaunchKernelGGL(k_transpose, dim3(16, 8, 8), dim3(256), 0, stream, x, xT);
    hipLaunchKernelGGL(k_gemm_qk, dim3(512), dim3(256), 0, stream,
                       xT, wqb, wkb, bq, bk, qb, kb);
    hipLaunchKernelGGL(k_gemm_max8, dim3(256), dim3(512), 0, stream, qb, kb, Mout);
    hipLaunchKernelGGL(k_softmax, dim3(8), dim3(256), 0, stream, Mout, wsm);
    hipLaunchKernelGGL(k_reduce_y, dim3(512), dim3(256), 0, stream, x, wsm, yv);
    hipLaunchKernelGGL(k_proto, dim3(512), dim3(64), 0, stream, W6, b6, yv, proto);
    hipLaunchKernelGGL(k_final, dim3(4096), dim3(256), 0, stream, x, proto, out);
}

// Round 8
// 103.003 us; speedup vs baseline: 1.3537x; 1.0016x over previous
//
#include <hip/hip_runtime.h>
#include <hip/hip_bf16.h>

typedef __bf16 bf16_t;
typedef __bf16 bf16x8 __attribute__((ext_vector_type(8)));
typedef float f32x4 __attribute__((ext_vector_type(4)));

#define B_   8
#define C_   512
#define HW_  1024
#define NPIX 8192

// ---- async global->LDS (16B per lane) ----
typedef __attribute__((address_space(3))) void lds_vp;
typedef const __attribute__((address_space(1))) void gbl_vp;
__device__ __forceinline__ void gload_lds16(const void* g, void* l) {
    __builtin_amdgcn_global_load_lds((gbl_vp*)g, (lds_vp*)l, 16, 0, 0);
}

// Stage a 128x64 bf16 tile (row-major, ld=ldk) into LDS [128][64] linearly.
__device__ __forceinline__ void stage128x64(const bf16_t* __restrict__ g, int ldk,
                                            bf16_t* lds, int tid) {
    int w64 = tid & ~63;
#pragma unroll
    for (int s = 0; s < 4; ++s) {
        int u = s * 256 + tid;
        const bf16_t* src = g + (size_t)(u >> 3) * ldk + (u & 7) * 8;
        gload_lds16((const void*)src, (void*)(lds + (size_t)(s * 256 + w64) * 8));
    }
}

// ---- K1a: convert weights to bf16 ----
__global__ void k_cvt_w(const float* __restrict__ Wq, const float* __restrict__ Wk,
                        bf16_t* __restrict__ wq, bf16_t* __restrict__ wk) {
    int i = blockIdx.x * 256 + threadIdx.x;
    wq[i] = (bf16_t)Wq[i];
    wk[i] = (bf16_t)Wk[i];
}

// ---- K1b: x [B,C,HW] f32 -> xT [B*HW, C] bf16 ----
__global__ void k_transpose(const float* __restrict__ x, bf16_t* __restrict__ xT) {
    __shared__ bf16_t tile[64 * 66];
    int p0 = blockIdx.x * 64, c0 = blockIdx.y * 64, b = blockIdx.z;
    int t = threadIdx.x;
#pragma unroll
    for (int s = 0; s < 16; ++s) {
        int u = s * 256 + t;
        int cr = u >> 6, pc = u & 63;
        tile[cr * 66 + pc] = (bf16_t)x[((size_t)(b * C_ + c0 + cr)) * HW_ + p0 + pc];
    }
    __syncthreads();
#pragma unroll
    for (int s = 0; s < 16; ++s) {
        int u = s * 256 + t;
        int pr = u >> 6, cc = u & 63;
        xT[((size_t)(b * HW_ + p0 + pr)) * C_ + c0 + cc] = tile[cc * 66 + pr];
    }
}

// ---- K2: q/k projection GEMM (m97 structure, 128x128 tiles) ----
__launch_bounds__(256, 2)
__global__ void k_gemm_qk(const bf16_t* __restrict__ xT,
                          const bf16_t* __restrict__ wq, const bf16_t* __restrict__ wk,
                          const float* __restrict__ bq, const float* __restrict__ bk,
                          bf16_t* __restrict__ qo, bf16_t* __restrict__ ko) {
    __shared__ bf16_t As[128 * 64];
    __shared__ bf16_t Bs[128 * 64];
    int bid = blockIdx.x;
    int mtile = bid >> 3;
    int nt = bid & 7;
    const bf16_t* wsel = (nt < 4) ? wq : wk;
    const float*  bsel = (nt < 4) ? bq : bk;
    bf16_t*       osel = (nt < 4) ? qo : ko;
    int nb = (nt & 3) * 128;
    int i0 = mtile * 128;
    int tid = threadIdx.x;
    int lane = tid & 63, w = tid >> 6;
    int wr = w >> 1, wc = w & 1, lr = lane & 15, lg = lane >> 4;

    f32x4 acc[4][4];
#pragma unroll
    for (int mi = 0; mi < 4; ++mi)
#pragma unroll
        for (int ni = 0; ni < 4; ++ni)
#pragma unroll
            for (int r = 0; r < 4; ++r) acc[mi][ni][r] = 0.f;

    for (int kt = 0; kt < 8; ++kt) {
        int k0 = kt * 64;
        stage128x64(xT + (size_t)i0 * 512 + k0, 512, As, tid);
        stage128x64(wsel + (size_t)nb * 512 + k0, 512, Bs, tid);
        __syncthreads();
#pragma unroll
        for (int kk = 0; kk < 2; ++kk) {
            bf16x8 af[4], bfr[4];
#pragma unroll
            for (int mi = 0; mi < 4; ++mi)
                af[mi] = *reinterpret_cast<const bf16x8*>(
                    &As[(wr * 64 + mi * 16 + lr) * 64 + kk * 32 + lg * 8]);
#pragma unroll
            for (int ni = 0; ni < 4; ++ni)
                bfr[ni] = *reinterpret_cast<const bf16x8*>(
                    &Bs[(wc * 64 + ni * 16 + lr) * 64 + kk * 32 + lg * 8]);
#pragma unroll
            for (int mi = 0; mi < 4; ++mi)
#pragma unroll
                for (int ni = 0; ni < 4; ++ni)
                    acc[mi][ni] = __builtin_amdgcn_mfma_f32_16x16x32_bf16(
                        af[mi], bfr[ni], acc[mi][ni], 0, 0, 0);
        }
        __syncthreads();
    }
#pragma unroll
    for (int ni = 0; ni < 4; ++ni) {
        int col = nb + wc * 64 + ni * 16 + lr;
        float bias = bsel[col];
#pragma unroll
        for (int mi = 0; mi < 4; ++mi) {
            int rowb = i0 + wr * 64 + mi * 16 + lg * 4;
#pragma unroll
            for (int r = 0; r < 4; ++r)
                osel[(size_t)(rowb + r) * 512 + col] = (bf16_t)(acc[mi][ni][r] + bias);
        }
    }
}

// ---- K3: score GEMM + per-key-image max, fragment-pipelined 8-phase ----
// 256 blocks = (q-panel 256 rows) x (key image). 32 K-tiles (4 n-chunks x 8).
// LDS: 8 regions [128 rows][128 B]; swizzle byte-in-row ^= (row&7)<<4
// (conflict-free, verified SQ_LDS_BANK_CONFLICT==0).
// SOFTWARE PIPELINE: phase p issues ds_reads for phase p+1 into the ALT
// register set (af[2][4], bf[2][4]); MFMA(p) consumes the set read at p-1.
// No read->MFMA dep inside a phase => LDS pipe fills under the matrix pipe.
// Ledger (iter i: ta=2i in d0, tb=2i+1 in d1, tc=2i+2, td=2i+3):
//   reads@ph_j are frags for ph_{j+1}: ph1->(d0,k0,m1) ph2->(d0,k1,m0)+B
//   ph3->(d0,k1,m1) ph4->(d1,k0,m0)+B ph5->(d1,k0,m1) ph6->(d1,k1,m0)+B
//   ph7->(d1,k1,m1) ph8->(d0,k0,m0)+B(next iter)
//   stages: ph1:A0d1(tb) ph2:A1d1(tb) ph3:GATE vmcnt(0)
//           ph4:B0d0+B1d0(tc) ph5:A0d0(tc) ph6:A1d0(tc) ph7:GATE vmcnt(0)
//           ph8:B0d1+B1d1(td)
// WAR rule used: stage(R) >= last-read-issue(R) + 2 phases (consumption by
// MFMA of the next phase forces read completion; barrier in between orders
// it against the stage). Verified per-region. RAW: each d-group fully
// staged+gated >=1 phase before its first fragment read-issue; gate's
// newest outstanding load is >=1 phase old (>L2 latency) so vmcnt(0) ~free.

#define STAGE_A(RH, D, T)                                                          \
    gload_lds16((const void*)(q + srcA + (size_t)((RH) * 128) * 512 +              \
                              ((T) & 7) * 64),                                     \
                (void*)(ldsb + (RH) * 32768 + (D) * 16384 + ldw));                 \
    gload_lds16((const void*)(q + srcA + (size_t)((RH) * 128 + 64) * 512 +         \
                              ((T) & 7) * 64),                                     \
                (void*)(ldsb + (RH) * 32768 + (D) * 16384 + 8192 + ldw));

#define STAGE_B(RH, D, T)                                                          \
    gload_lds16((const void*)(kb + srcB +                                          \
                              (size_t)(((T) >> 3) * 256 + (RH) * 128) * 512 +      \
                              ((T) & 7) * 64),                                     \
                (void*)(ldsb + 65536 + (RH) * 32768 + (D) * 16384 + ldw));         \
    gload_lds16((const void*)(kb + srcB +                                          \
                              (size_t)(((T) >> 3) * 256 + (RH) * 128 + 64) * 512 + \
                              ((T) & 7) * 64),                                     \
                (void*)(ldsb + 65536 + (RH) * 32768 + (D) * 16384 + 8192 + ldw));

// RSET: af set to fill (for next phase) from region (RD,RKH,RMH);
// RBF/RBSET: whether/where to fill bf; CSET/CMH/CBSET: MFMA consumes.
#define PHASE(RSET, RD, RKH, RMH, RBF, RBSET, CSET, CMH, CBSET, STG, VM)           \
    {                                                                              \
        const char* rAb = ldsb + wr * 32768 + (RD) * 16384;                        \
        _Pragma("unroll")                                                          \
        for (int mi = 0; mi < 4; ++mi)                                             \
            af[RSET][mi] = *(const bf16x8*)(rAb + (aswz ^ ((RKH) * 64)) +          \
                                            ((RMH) * 4 + mi) * 2048);              \
        if (RBF) {                                                                 \
            const char* rBb = ldsb + 65536 + (wc >> 1) * 32768 + (RD) * 16384;     \
            _Pragma("unroll")                                                      \
            for (int ni = 0; ni < 4; ++ni)                                         \
                bf[RBSET][ni] = *(const bf16x8*)(rBb + (bswz ^ ((RKH) * 64)) +     \
                                                 ni * 2048);                       \
        }                                                                          \
        STG;                                                                       \
        __builtin_amdgcn_s_setprio(1);                                             \
        _Pragma("unroll")                                                          \
        for (int mi = 0; mi < 4; ++mi)                                             \
            _Pragma("unroll")                                                      \
            for (int ni = 0; ni < 4; ++ni)                                         \
                acc[(CMH) * 4 + mi][ni] = __builtin_amdgcn_mfma_f32_16x16x32_bf16( \
                    af[CSET][mi], bf[CBSET][ni], acc[(CMH) * 4 + mi][ni], 0, 0, 0);\
        __builtin_amdgcn_s_setprio(0);                                             \
        VM;                                                                        \
        __builtin_amdgcn_s_barrier();                                              \
    }

__global__ __launch_bounds__(512, 2)
void k_gemm_max8(const bf16_t* __restrict__ q, const bf16_t* __restrict__ kp,
                 float* __restrict__ Mout) {
    __shared__ __align__(16) bf16_t lds[65536];   // 128 KiB
    char* ldsb = (char*)lds;
    int bid = blockIdx.x;           // 256 blocks
    int img = bid & 7;              // XCD-local key image
    int qp = bid >> 3;              // 0..31
    int i0 = qp * 256;
    const bf16_t* kb = kp + (size_t)img * HW_ * C_;
    int tid = threadIdx.x;
    int lane = tid & 63, w = tid >> 6;
    int wr = w >> 2, wc = w & 3;    // 2 x 4 wave grid
    int lr = lane & 15, lg = lane >> 4;
    int kswz = (lg ^ (lr & 7)) << 4;
    int aswz = lr * 128 + kswz;
    int bswz = ((wc & 1) * 64 + lr) * 128 + kswz;

    // staging: inverse-swizzled global source, linear LDS dest
    int srow = tid >> 3;
    int sk = (((tid & 7) ^ ((tid >> 3) & 7))) << 3;
    size_t srcA = (size_t)(i0 + srow) * 512 + sk;
    size_t srcB = (size_t)srow * 512 + sk;
    int ldw = (tid >> 6) * 1024;

    f32x4 acc[8][4];
    bf16x8 af[2][4], bf[2][4];
    float rm[8][4];
#pragma unroll
    for (int mi = 0; mi < 8; ++mi)
#pragma unroll
        for (int ni = 0; ni < 4; ++ni)
#pragma unroll
            for (int r = 0; r < 4; ++r) acc[mi][ni][r] = 0.f;
#pragma unroll
    for (int mi = 0; mi < 8; ++mi)
#pragma unroll
        for (int r = 0; r < 4; ++r) rm[mi][r] = -3.4e38f;

    // prologue: stage t0 d0 (4 regions), t1 d1 B-halves (ph8' slot)
    STAGE_B(0, 0, 0) STAGE_B(1, 0, 0) STAGE_A(0, 0, 0) STAGE_A(1, 0, 0)
    STAGE_B(0, 1, 1) STAGE_B(1, 1, 1)
    asm volatile("s_waitcnt vmcnt(4)" ::: "memory");
    __builtin_amdgcn_s_barrier();
    // prologue fragment reads for ph1: af[0] <- (d0,k0,m0), bf[0] <- B(d0,k0)
    {
        const char* rAb = ldsb + wr * 32768;
#pragma unroll
        for (int mi = 0; mi < 4; ++mi)
            af[0][mi] = *(const bf16x8*)(rAb + aswz + mi * 2048);
        const char* rBb = ldsb + 65536 + (wc >> 1) * 32768;
#pragma unroll
        for (int ni = 0; ni < 4; ++ni)
            bf[0][ni] = *(const bf16x8*)(rBb + bswz + ni * 2048);
    }

    for (int i = 0; i < 16; ++i) {
        int tb = 2 * i + 1, tc = 2 * i + 2, td = 2 * i + 3;
        bool s = (i < 15);
        // ph1: MFMA(d0,k0,m0) set0/bf0 ; read af1<-(d0,k0,m1) ; stage A0d1(tb)
        PHASE(1, 0, 0, 1, 0, 0,  0, 0, 0, { STAGE_A(0, 1, tb) }, {})
        // ph2: MFMA m1 set1/bf0 ; read af0<-(d0,k1,m0), bf1<-B(d0,k1) ; stage A1d1(tb)
        PHASE(0, 0, 1, 0, 1, 1,  1, 1, 0, { STAGE_A(1, 1, tb) }, {})
        // ph3: MFMA m0 set0/bf1 ; read af1<-(d0,k1,m1) ; GATE
        PHASE(1, 0, 1, 1, 0, 0,  0, 0, 1, {},
              { asm volatile("s_waitcnt vmcnt(0)" ::: "memory"); })
        // ph4: MFMA m1 set1/bf1 ; read af0<-(d1,k0,m0), bf0<-B(d1,k0) ; stage B0d0+B1d0(tc)
        PHASE(0, 1, 0, 0, 1, 0,  1, 1, 1,
              { if (s) { STAGE_B(0, 0, tc) STAGE_B(1, 0, tc) } }, {})
        // ph5: MFMA m0 set0/bf0 ; read af1<-(d1,k0,m1) ; stage A0d0(tc)
        PHASE(1, 1, 0, 1, 0, 0,  0, 0, 0, { if (s) { STAGE_A(0, 0, tc) } }, {})
        // ph6: MFMA m1 set1/bf0 ; read af0<-(d1,k1,m0), bf1<-B(d1,k1) ; stage A1d0(tc)
        PHASE(0, 1, 1, 0, 1, 1,  1, 1, 0, { if (s) { STAGE_A(1, 0, tc) } }, {})
        // ph7: MFMA m0 set0/bf1 ; read af1<-(d1,k1,m1) ; GATE
        PHASE(1, 1, 1, 1, 0, 0,  0, 0, 1, {},
              { asm volatile("s_waitcnt vmcnt(0)" ::: "memory"); })
        // ph8: MFMA m1 set1/bf1 ; read af0<-(d0,k0,m0), bf0<-B(d0,k0) [next iter] ;
        //      stage B0d1+B1d1(td)
        PHASE(0, 0, 0, 0, 1, 0,  1, 1, 1,
              { if (s) { STAGE_B(0, 1, td) STAGE_B(1, 1, td) } }, {})
        if ((i & 3) == 3) {   // n-chunk complete: fold acc into rm, reset acc
#pragma unroll
            for (int mi = 0; mi < 8; ++mi)
#pragma unroll
                for (int r = 0; r < 4; ++r) {
                    float v = fmaxf(fmaxf(acc[mi][0][r], acc[mi][1][r]),
                                    fmaxf(acc[mi][2][r], acc[mi][3][r]));
                    rm[mi][r] = fmaxf(rm[mi][r], v);
#pragma unroll
                    for (int ni = 0; ni < 4; ++ni) acc[mi][ni][r] = 0.f;
                }
        }
    }

    // epilogue: reduce across 16 col-lanes, then across the 4 wc waves
#pragma unroll
    for (int mi = 0; mi < 8; ++mi)
#pragma unroll
        for (int r = 0; r < 4; ++r) {
            float v = rm[mi][r];
#pragma unroll
            for (int off = 1; off < 16; off <<= 1) v = fmaxf(v, __shfl_xor(v, off));
            rm[mi][r] = v;
        }
    float* sm = (float*)lds;
    if (lr == 0) {
#pragma unroll
        for (int mi = 0; mi < 8; ++mi)
#pragma unroll
            for (int r = 0; r < 4; ++r)
                sm[wc * 256 + wr * 128 + mi * 16 + lg * 4 + r] = rm[mi][r];
    }
    __syncthreads();
    if (tid < 256) {
        float v = fmaxf(fmaxf(sm[tid], sm[256 + tid]),
                        fmaxf(sm[512 + tid], sm[768 + tid]));
        Mout[(size_t)(i0 + tid) * 8 + img] = v;
    }
}

// ---- K4: mean over key images, scale, softmax per query image ----
__global__ void k_softmax(const float* __restrict__ Mout, float* __restrict__ wsm) {
    int b = blockIdx.x;
    int t = threadIdx.x;
    __shared__ float red[16];
    const float scale = 0.044194173824159216f;  // 1/sqrt(512)
    float s[4];
#pragma unroll
    for (int i = 0; i < 4; ++i) {
        int p = t + i * 256;
        const float* row = &Mout[(size_t)(b * 1024 + p) * 8];
        float acc = 0.f;
#pragma unroll
        for (int j = 0; j < 8; ++j) acc += row[j];
        s[i] = acc * (scale / 8.0f);
    }
    float m = fmaxf(fmaxf(s[0], s[1]), fmaxf(s[2], s[3]));
#pragma unroll
    for (int off = 1; off < 64; off <<= 1) m = fmaxf(m, __shfl_xor(m, off));
    if ((t & 63) == 0) red[t >> 6] = m;
    __syncthreads();
    float m4 = fmaxf(fmaxf(red[0], red[1]), fmaxf(red[2], red[3]));
    float e[4], sum = 0.f;
#pragma unroll
    for (int i = 0; i < 4; ++i) { e[i] = __expf(s[i] - m4); sum += e[i]; }
#pragma unroll
    for (int off = 1; off < 64; off <<= 1) sum += __shfl_xor(sum, off);
    if ((t & 63) == 0) red[8 + (t >> 6)] = sum;
    __syncthreads();
    float tot = red[8] + red[9] + red[10] + red[11];
    float inv = 1.0f / tot;
#pragma unroll
    for (int i = 0; i < 4; ++i) wsm[b * 1024 + t + i * 256] = e[i] * inv;
}

// ---- K5: y[c] = mean_{b,p} x[b,c,p] * w[b,p] ----
__global__ void k_reduce_y(const float* __restrict__ x, const float* __restrict__ wsm,
                           float* __restrict__ y) {
    int c = blockIdx.x;
    int t = threadIdx.x;
    float acc = 0.f;
    for (int b = 0; b < 8; ++b) {
        const float* xb = x + ((size_t)(b * C_ + c)) * HW_;
        const float* wb = wsm + b * HW_;
#pragma unroll
        for (int i = 0; i < 4; ++i) {
            int p = t + i * 256;
            acc += xb[p] * wb[p];
        }
    }
#pragma unroll
    for (int off = 1; off < 64; off <<= 1) acc += __shfl_xor(acc, off);
    __shared__ float red[4];
    if ((t & 63) == 0) red[t >> 6] = acc;
    __syncthreads();
    if (t == 0) y[c] = (red[0] + red[1] + red[2] + red[3]) * (1.0f / 8192.0f);
}

// ---- K6: x_proto[d] = W6[d,:] . y + b6[d] ----
__global__ void k_proto(const float* __restrict__ W6, const float* __restrict__ b6,
                        const float* __restrict__ y, float* __restrict__ proto) {
    int d = blockIdx.x;
    int lane = threadIdx.x;
    float acc = 0.f;
#pragma unroll
    for (int i = 0; i < 8; ++i)
        acc += W6[(size_t)d * C_ + lane + i * 64] * y[lane + i * 64];
#pragma unroll
    for (int off = 1; off < 64; off <<= 1) acc += __shfl_xor(acc, off);
    if (lane == 0) proto[d] = acc + b6[d];
}

// ---- K7: out = x * proto[c] ----
__global__ void k_final(const float* __restrict__ x, const float* __restrict__ proto,
                        float* __restrict__ out) {
    int idx = blockIdx.x * 256 + threadIdx.x;
    float4 v = ((const float4*)x)[idx];
    int c = (idx >> 8) & 511;
    float p = proto[c];
    v.x *= p; v.y *= p; v.z *= p; v.w *= p;
    ((float4*)out)[idx] = v;
}

extern "C" void kernel_launch(void* const* d_in, const int* in_sizes, int n_in,
                              void* d_out, int out_size, void* d_ws, size_t ws_size,
                              hipStream_t stream) {
    const float* x  = (const float*)d_in[0];
    const float* Wq = (const float*)d_in[1];
    const float* bq = (const float*)d_in[2];
    const float* Wk = (const float*)d_in[3];
    const float* bk = (const float*)d_in[4];
    const float* W6 = (const float*)d_in[5];
    const float* b6 = (const float*)d_in[6];
    float* out = (float*)d_out;

    char* ws = (char*)d_ws;
    bf16_t* xT    = (bf16_t*)(ws);                 // 8.4 MB (dead after k_gemm_qk)
    float*  Mout  = (float*)(ws);                  // 8192*8*4 = 256 KB, aliases xT
    bf16_t* wqb   = (bf16_t*)(ws + 8388608);
    bf16_t* wkb   = (bf16_t*)(ws + 8912896);
    bf16_t* qb    = (bf16_t*)(ws + 9437184);
    bf16_t* kb    = (bf16_t*)(ws + 17825792);
    float*  wsm   = (float*)(ws + 26476544);
    float*  yv    = (float*)(ws + 26509312);
    float*  proto = (float*)(ws + 26511360);

    hipLaunchKernelGGL(k_cvt_w, dim3(1024), dim3(256), 0, stream, Wq, Wk, wqb, wkb);
    hipLaunchKernelGGL(k_transpose, dim3(16, 8, 8), dim3(256), 0, stream, x, xT);
    hipLaunchKernelGGL(k_gemm_qk, dim3(512), dim3(256), 0, stream,
                       xT, wqb, wkb, bq, bk, qb, kb);
    hipLaunchKernelGGL(k_gemm_max8, dim3(256), dim3(512), 0, stream, qb, kb, Mout);
    hipLaunchKernelGGL(k_softmax, dim3(8), dim3(256), 0, stream, Mout, wsm);
    hipLaunchKernelGGL(k_reduce_y, dim3(512), dim3(256), 0, stream, x, wsm, yv);
    hipLaunchKernelGGL(k_proto, dim3(512), dim3(64), 0, stream, W6, b6, yv, proto);
    hipLaunchKernelGGL(k_final, dim3(4096), dim3(256), 0, stream, x, proto, out);
}